// Round 1
// baseline (523.887 us; speedup 1.0000x reference)
//
#include <hip/hip_runtime.h>

#define NQn 10000
#define NSn 10000
#define Hh  32
#define FDIM 3840   // K(15) * 2*IN_CH(256)

// ---------------------------------------------------------------------------
// Stage 1: per-query block. Computes influence weights, LRF-MLP features,
// neighbor aggregation -> wf[n][k*256 + q*64 + c]   (f = GEMM reduction dim)
// FUSED=true: also does the weights matmul per block (fallback when ws too small)
// ---------------------------------------------------------------------------
template<bool FUSED>
__global__ __launch_bounds__(256) void ekp_stage1(
    const float* __restrict__ q_pts,
    const float* __restrict__ s_pts,
    const int*   __restrict__ nbi,
    const float* __restrict__ x,
    const float* __restrict__ q_lrf,
    const float* __restrict__ s_lrf,
    const float* __restrict__ weights,
    const float* __restrict__ kp,
    const float* __restrict__ mlp_w,
    const float* __restrict__ mlp_b,
    float* __restrict__ wf_out,
    float* __restrict__ out)
{
  const int n = blockIdx.x;
  const int tid = threadIdx.x;

  __shared__ float sQ[36];          // q_lrf[q][d][e]
  __shared__ float sKP[45];         // kernel points [15][3]
  __shared__ float sMW[36][32];     // mlp_w
  __shared__ float sMB[32];         // mlp_b
  __shared__ int   sIdx[32];
  __shared__ int   sShad[32];
  __shared__ float sNbr[32][3];     // centered neighbor coords
  __shared__ float sLrf[32][37];    // gathered s_lrf (padded: stride 37, gcd(5,32)=1)
  __shared__ float sW[4][15][32];   // influence weights [q][k][h]
  __shared__ float sNbx[32][4][65]; // neighbor features [h][q][c] (c<32 x, c>=32 lrf_feat)

  if (tid < 36) sQ[tid]  = q_lrf[(size_t)n*36 + tid];
  if (tid < 45) sKP[tid] = kp[tid];
  if (tid < 32) sMB[tid] = mlp_b[tid];
  for (int i = tid; i < 36*32; i += 256) sMW[i >> 5][i & 31] = mlp_w[i];
  if (tid < 32) {
    int idx = nbi[(size_t)n*Hh + tid];
    int sh = (idx >= NSn) ? 1 : 0;
    sShad[tid] = sh;
    sIdx[tid]  = sh ? 0 : idx;
  }
  __syncthreads();

  // gather neighbor coords (value irrelevant for shadow: w forced to 0)
  if (tid < 96) {
    int h = tid / 3, d = tid - h*3;
    float v = sShad[h] ? 0.f : s_pts[(size_t)sIdx[h]*3 + d];
    sNbr[h][d] = v - q_pts[(size_t)n*3 + d];
  }
  // gather neighbor LRFs (zeroed for shadow, matching s_lrf_pad)
  {
    int h = tid >> 3, j0 = tid & 7;
    const float* src = s_lrf + (size_t)sIdx[h]*36;
    float z = sShad[h] ? 0.f : 1.f;
    for (int j = j0; j < 36; j += 8) sLrf[h][j] = z * src[j];
  }
  // gather neighbor x features (zero row for shadow)
  for (int i = tid; i < Hh*128; i += 256) {
    int h = i >> 7, c = i & 127;
    float v = sShad[h] ? 0.f : x[(size_t)sIdx[h]*128 + c];
    sNbx[h][c >> 5][c & 31] = v;
  }
  __syncthreads();

  // ---- kernel-point influence weights: w[q][k][h] ----
  {
    int q = tid >> 6, l = tid & 63;
    int h = l & 31, kh = l >> 5;
    float a0 = 0.f, a1 = 0.f, a2 = 0.f;
    #pragma unroll
    for (int d = 0; d < 3; ++d) {
      float nd = sNbr[h][d];
      a0 += nd * sQ[q*9 + d*3 + 0];
      a1 += nd * sQ[q*9 + d*3 + 1];
      a2 += nd * sQ[q*9 + d*3 + 2];
    }
    float z = sShad[h] ? 0.f : 1.f;
    int k0 = kh * 8;
    int kend = k0 + (kh ? 7 : 8);
    for (int k = k0; k < kend; ++k) {
      float d0 = a0 - sKP[k*3+0];
      float d1 = a1 - sKP[k*3+1];
      float d2 = a2 - sKP[k*3+2];
      float w = 1.f - sqrtf(d0*d0 + d1*d1 + d2*d2) * (1.0f/1.2f);
      sW[q][k][h] = z * fmaxf(w, 0.f);
    }
  }
  // ---- LRF MLP: aligned_lrf (36) -> lrf_feat (32) ----
  {
    int q = tid >> 6, l = tid & 63;
    int h = l & 31, mh = l >> 5;
    float fi[36];
    #pragma unroll
    for (int s = 0; s < 4; ++s)
      #pragma unroll
      for (int a = 0; a < 3; ++a)
        #pragma unroll
        for (int c = 0; c < 3; ++c) {
          float accv = 0.f;
          #pragma unroll
          for (int b = 0; b < 3; ++b)
            accv += sQ[q*9 + b*3 + a] * sLrf[h][s*9 + b*3 + c];  // q_lrf^T @ s_lrf
          fi[s*9 + a*3 + c] = accv;
        }
    float z = sShad[h] ? 0.f : 1.f;   // mask multiplies bias too
    int m0 = mh * 16;
    for (int mm = 0; mm < 16; ++mm) {
      int m = m0 + mm;
      float accv = sMB[m];
      #pragma unroll
      for (int j = 0; j < 36; ++j) accv += fi[j] * sMW[j][m];
      sNbx[h][q][32 + m] = z * accv;
    }
  }
  __syncthreads();

  // ---- neighbor aggregation: wf[q][k][c] = sum_h w[q][k][h]*nbx[h][q][c] ----
  float acc[15];
  const int q = tid >> 6, cch = tid & 63;
  #pragma unroll
  for (int k = 0; k < 15; ++k) acc[k] = 0.f;
  for (int h = 0; h < Hh; ++h) {
    float v = sNbx[h][q][cch];
    #pragma unroll
    for (int k = 0; k < 15; ++k) acc[k] += sW[q][k][h] * v;
  }

  if constexpr (!FUSED) {
    size_t base = (size_t)n * FDIM + q*64 + cch;
    #pragma unroll
    for (int k = 0; k < 15; ++k) wf_out[base + k*256] = acc[k];
  } else {
    __shared__ float sWF[FDIM];
    __shared__ float sRed[2][128];
    #pragma unroll
    for (int k = 0; k < 15; ++k) sWF[k*256 + q*64 + cch] = acc[k];
    __syncthreads();
    int o = tid & 127, part = tid >> 7;
    const float* wp = weights + (size_t)part*1920*128 + o;
    const float* wfp = sWF + part*1920;
    float oa = 0.f;
    #pragma unroll 8
    for (int f = 0; f < 1920; ++f)
      oa += wfp[f] * wp[(size_t)f*128];
    sRed[part][o] = oa;
    __syncthreads();
    if (tid < 128) out[(size_t)n*128 + tid] = sRed[0][tid] + sRed[1][tid];
  }
}

// ---------------------------------------------------------------------------
// Stage 2: out[10000,128] = WF[10000,3840] @ W[3840,128]   (f32 vector GEMM)
// ---------------------------------------------------------------------------
__global__ __launch_bounds__(256) void ekp_gemm(
    const float* __restrict__ A,   // [M][FDIM]
    const float* __restrict__ B,   // [FDIM][128]  == weights flat
    float* __restrict__ C,         // [M][128]
    int M)
{
  __shared__ float As[32][36];     // [kk][row], padded for 16B-aligned float4
  __shared__ float Bs[32][128];
  const int tid  = threadIdx.x;
  const int row0 = blockIdx.x * 32;
  const int tr = (tid >> 5) << 2;  // micro-tile rows: 0,4,...,28
  const int tc = (tid & 31) << 2;  // micro-tile cols: 0,4,...,124
  float acc[4][4];
  #pragma unroll
  for (int i = 0; i < 4; ++i)
    #pragma unroll
    for (int j = 0; j < 4; ++j) acc[i][j] = 0.f;

  const int lr = tid >> 3;           // A-load row
  const int lk = (tid & 7) << 2;     // A-load k offset
  const bool arow_ok = (row0 + lr) < M;
  const float* aptr = A + (size_t)(row0 + lr)*FDIM + lk;

  for (int kc = 0; kc < FDIM; kc += 32) {
    float4 av = arow_ok ? *(const float4*)(aptr + kc)
                        : make_float4(0.f, 0.f, 0.f, 0.f);
    As[lk+0][lr] = av.x;
    As[lk+1][lr] = av.y;
    As[lk+2][lr] = av.z;
    As[lk+3][lr] = av.w;
    #pragma unroll
    for (int p = 0; p < 4; ++p) {
      int i = tid + p*256;
      int kk = i >> 5, c4 = (i & 31) << 2;
      *(float4*)&Bs[kk][c4] = *(const float4*)&B[(size_t)(kc+kk)*128 + c4];
    }
    __syncthreads();
    #pragma unroll
    for (int kk = 0; kk < 32; ++kk) {
      float4 a = *(const float4*)&As[kk][tr];
      float4 b = *(const float4*)&Bs[kk][tc];
      acc[0][0] += a.x*b.x; acc[0][1] += a.x*b.y; acc[0][2] += a.x*b.z; acc[0][3] += a.x*b.w;
      acc[1][0] += a.y*b.x; acc[1][1] += a.y*b.y; acc[1][2] += a.y*b.z; acc[1][3] += a.y*b.w;
      acc[2][0] += a.z*b.x; acc[2][1] += a.z*b.y; acc[2][2] += a.z*b.z; acc[2][3] += a.z*b.w;
      acc[3][0] += a.w*b.x; acc[3][1] += a.w*b.y; acc[3][2] += a.w*b.z; acc[3][3] += a.w*b.w;
    }
    __syncthreads();
  }
  #pragma unroll
  for (int i = 0; i < 4; ++i) {
    int gr = row0 + tr + i;
    if (gr < M)
      *(float4*)&C[(size_t)gr*128 + tc] =
        make_float4(acc[i][0], acc[i][1], acc[i][2], acc[i][3]);
  }
}

extern "C" void kernel_launch(void* const* d_in, const int* in_sizes, int n_in,
                              void* d_out, int out_size, void* d_ws, size_t ws_size,
                              hipStream_t stream) {
  const float* q_pts   = (const float*)d_in[0];
  const float* s_pts   = (const float*)d_in[1];
  const int*   nbi     = (const int*)  d_in[2];
  const float* x       = (const float*)d_in[3];
  const float* q_lrf   = (const float*)d_in[4];
  const float* s_lrf   = (const float*)d_in[5];
  const float* weights = (const float*)d_in[6];
  const float* kp      = (const float*)d_in[7];
  const float* mlp_w   = (const float*)d_in[8];
  const float* mlp_b   = (const float*)d_in[9];
  float* out = (float*)d_out;

  const size_t need = (size_t)NQn * FDIM * sizeof(float);
  if (ws_size >= need) {
    float* wf = (float*)d_ws;
    ekp_stage1<false><<<NQn, 256, 0, stream>>>(q_pts, s_pts, nbi, x, q_lrf, s_lrf,
                                               weights, kp, mlp_w, mlp_b, wf, out);
    int g2 = (NQn + 31) / 32;
    ekp_gemm<<<g2, 256, 0, stream>>>(wf, weights, out, NQn);
  } else {
    ekp_stage1<true><<<NQn, 256, 0, stream>>>(q_pts, s_pts, nbi, x, q_lrf, s_lrf,
                                              weights, kp, mlp_w, mlp_b, nullptr, out);
  }
}

// Round 2
// 204.063 us; speedup vs baseline: 2.5673x; 2.5673x over previous
//
#include <hip/hip_runtime.h>

#define NQn 10000
#define NSn 10000
#define Hh  32
#define FDIM 3840   // K(15) * 2*IN_CH(256)

typedef _Float16 f16x8 __attribute__((ext_vector_type(8)));
typedef float    f32x4 __attribute__((ext_vector_type(4)));

__device__ __forceinline__ unsigned pack2h(float a, float b) {
  union { _Float16 h; unsigned short u; } ua, ub;
  ua.h = (_Float16)a; ub.h = (_Float16)b;
  return (unsigned)ua.u | ((unsigned)ub.u << 16);
}

// ---------------------------------------------------------------------------
// Prep: Wt[n][k] = fp16(weights[k][n])   (transposed so GEMM B-frags are
// K-contiguous 16B ds_read/loads)
// ---------------------------------------------------------------------------
__global__ __launch_bounds__(256) void ekp_prep(const float* __restrict__ w,
                                                _Float16* __restrict__ wt) {
  const int n = blockIdx.x;
  for (int k = threadIdx.x; k < FDIM; k += 256)
    wt[(size_t)n * FDIM + k] = (_Float16)w[(size_t)k * 128 + n];
}

// ---------------------------------------------------------------------------
// Stage 1: per-query block.
//  - influence weights -> sWb[q][k(16,pad)][h]        (fp16, MFMA A-frags)
//  - x gather + LRF-MLP -> sNbxT[q][c(64)][h]         (fp16, MFMA B-frags)
//  - aggregation wf[q][k][c] = w @ nbx  via 4 MFMAs/wave (K=32=H exactly)
// wf written fp16 to workspace.
// ---------------------------------------------------------------------------
__global__ __launch_bounds__(256, 4) void ekp_stage1b(
    const float* __restrict__ q_pts, const float* __restrict__ s_pts,
    const int*   __restrict__ nbi,   const float* __restrict__ x,
    const float* __restrict__ q_lrf, const float* __restrict__ s_lrf,
    const float* __restrict__ kp,    const float* __restrict__ mlp_w,
    const float* __restrict__ mlp_b, _Float16* __restrict__ wf_out)
{
  const int n = blockIdx.x;
  const int tid = threadIdx.x;
  const int lane = tid & 63;
  const int wv = tid >> 6;          // wave id == q (0..3)

  __shared__ float sQ[36];
  __shared__ float sKP[45];
  __shared__ float sMW[36][32];
  __shared__ float sMB[32];
  __shared__ int   sIdx[32];
  __shared__ int   sShad[32];
  __shared__ float sNbr[32][3];
  __shared__ float sLrf[32][37];
  __shared__ alignas(16) _Float16 sWb[4][16][40];    // [q][k][h], 80B rows
  __shared__ alignas(16) _Float16 sNbxT[4][64][40];  // [q][c][h], 80B rows

  if (tid < 36) sQ[tid]  = q_lrf[(size_t)n*36 + tid];
  if (tid < 45) sKP[tid] = kp[tid];
  if (tid < 32) sMB[tid] = mlp_b[tid];
  for (int i = tid; i < 36*32; i += 256) sMW[i >> 5][i & 31] = mlp_w[i];
  if (tid < 32) {
    int idx = nbi[(size_t)n*Hh + tid];
    int sh = (idx >= NSn) ? 1 : 0;
    sShad[tid] = sh;
    sIdx[tid]  = sh ? 0 : idx;
  }
  __syncthreads();

  // centered neighbor coords
  if (tid < 96) {
    int h = tid / 3, d = tid - h*3;
    float v = sShad[h] ? 0.f : s_pts[(size_t)sIdx[h]*3 + d];
    sNbr[h][d] = v - q_pts[(size_t)n*3 + d];
  }
  // gather neighbor LRFs (zeroed for shadow)
  {
    int h = tid >> 3, j0 = tid & 7;
    const float* src = s_lrf + (size_t)sIdx[h]*36;
    float z = sShad[h] ? 0.f : 1.f;
    for (int j = j0; j < 36; j += 8) sLrf[h][j] = z * src[j];
  }
  // gather x -> sNbxT[q][c][h] (transposed, fp16, packed pair-dword stores)
  #pragma unroll
  for (int it = 0; it < 4; ++it) {
    int i = tid + it*256;            // [0,1024)
    int cc = i & 127;                // full channel 0..127
    int h0 = (i >> 7) * 4;           // h group of 4
    int q = cc >> 5, c = cc & 31;
    float v0 = sShad[h0+0] ? 0.f : x[(size_t)sIdx[h0+0]*128 + cc];
    float v1 = sShad[h0+1] ? 0.f : x[(size_t)sIdx[h0+1]*128 + cc];
    float v2 = sShad[h0+2] ? 0.f : x[(size_t)sIdx[h0+2]*128 + cc];
    float v3 = sShad[h0+3] ? 0.f : x[(size_t)sIdx[h0+3]*128 + cc];
    uint2 pk;
    pk.x = pack2h(v0, v1);
    pk.y = pack2h(v2, v3);
    *reinterpret_cast<uint2*>(&sNbxT[q][c][h0]) = pk;
  }
  __syncthreads();

  // ---- influence weights -> sWb (k row 15 zeroed: MFMA pad) ----
  {
    int h = lane & 31, kh = lane >> 5;
    float a0 = 0.f, a1 = 0.f, a2 = 0.f;
    #pragma unroll
    for (int d = 0; d < 3; ++d) {
      float nd = sNbr[h][d];
      a0 += nd * sQ[wv*9 + d*3 + 0];
      a1 += nd * sQ[wv*9 + d*3 + 1];
      a2 += nd * sQ[wv*9 + d*3 + 2];
    }
    float z = sShad[h] ? 0.f : 1.f;
    int k0 = kh * 8, kend = kh ? 15 : 8;
    for (int k = k0; k < kend; ++k) {
      float d0 = a0 - sKP[k*3+0];
      float d1 = a1 - sKP[k*3+1];
      float d2 = a2 - sKP[k*3+2];
      float wgt = 1.f - sqrtf(d0*d0 + d1*d1 + d2*d2) * (1.0f/1.2f);
      sWb[wv][k][h] = (_Float16)(z * fmaxf(wgt, 0.f));
    }
    if (kh) sWb[wv][15][h] = (_Float16)0.f;
  }
  // ---- LRF MLP: fi(36) -> 16 outputs/thread -> sNbxT[q][32+m][h] ----
  {
    int h = lane & 31, mh = lane >> 5;
    float fi[36];
    #pragma unroll
    for (int s = 0; s < 4; ++s)
      #pragma unroll
      for (int a = 0; a < 3; ++a)
        #pragma unroll
        for (int c = 0; c < 3; ++c) {
          float accv = 0.f;
          #pragma unroll
          for (int b = 0; b < 3; ++b)
            accv += sQ[wv*9 + b*3 + a] * sLrf[h][s*9 + b*3 + c];
          fi[s*9 + a*3 + c] = accv;
        }
    float z = sShad[h] ? 0.f : 1.f;
    int m0 = mh * 16;
    float av[16];
    #pragma unroll
    for (int m = 0; m < 16; ++m) av[m] = sMB[m0 + m];
    #pragma unroll
    for (int j = 0; j < 36; ++j) {
      float fj = fi[j];
      #pragma unroll
      for (int g = 0; g < 4; ++g) {
        float4 w4 = *reinterpret_cast<const float4*>(&sMW[j][m0 + g*4]);
        av[g*4+0] += fj * w4.x;
        av[g*4+1] += fj * w4.y;
        av[g*4+2] += fj * w4.z;
        av[g*4+3] += fj * w4.w;
      }
    }
    #pragma unroll
    for (int m = 0; m < 16; ++m)
      sNbxT[wv][32 + m0 + m][h] = (_Float16)(z * av[m]);
  }
  __syncthreads();

  // ---- aggregation via MFMA: C[k][c] = sum_h w[k][h] * nbx[h][c] ----
  {
    const int l15 = lane & 15, lg = lane >> 4;
    f16x8 a = *reinterpret_cast<const f16x8*>(&sWb[wv][l15][lg*8]);
    #pragma unroll
    for (int ni = 0; ni < 4; ++ni) {
      f16x8 b = *reinterpret_cast<const f16x8*>(&sNbxT[wv][ni*16 + l15][lg*8]);
      f32x4 acc = {0.f, 0.f, 0.f, 0.f};
      acc = __builtin_amdgcn_mfma_f32_16x16x32_f16(a, b, acc, 0, 0, 0);
      int col = wv*64 + ni*16 + l15;
      #pragma unroll
      for (int v = 0; v < 4; ++v) {
        int k = lg*4 + v;
        if (k < 15)
          wf_out[(size_t)n*FDIM + k*256 + col] = (_Float16)acc[v];
      }
    }
  }
}

// ---------------------------------------------------------------------------
// Stage 2: out[M,128] = wf[M,3840] @ W[3840,128]  (fp16 MFMA, f32 accum)
// BM=32, BN=64, BK=64; 4 waves, each 16x32 output.
// ---------------------------------------------------------------------------
__global__ __launch_bounds__(256, 4) void ekp_gemm_f16(
    const _Float16* __restrict__ A,   // [M][FDIM]
    const _Float16* __restrict__ Bt,  // [128][FDIM] (transposed weights)
    float* __restrict__ C, int M)
{
  __shared__ alignas(16) _Float16 As[32][72];
  __shared__ alignas(16) _Float16 Bs[64][72];
  const int tid = threadIdx.x;
  const int lane = tid & 63;
  const int w = tid >> 6;
  const int wr = w >> 1, wc = w & 1;
  const int r0 = blockIdx.x * 32, c0 = blockIdx.y * 64;
  const int l15 = lane & 15, lg = lane >> 4;

  f32x4 acc0 = {0.f,0.f,0.f,0.f}, acc1 = {0.f,0.f,0.f,0.f};

  const int ar = tid >> 3;           // staging row 0..31
  const int ak = (tid & 7) << 3;     // k offset 0..56
  const bool aok = (r0 + ar) < M;
  const _Float16* ap  = A  + (size_t)(r0 + ar)*FDIM + ak;
  const _Float16* bp0 = Bt + (size_t)(c0 + ar)*FDIM + ak;
  const _Float16* bp1 = Bt + (size_t)(c0 + 32 + ar)*FDIM + ak;
  const f16x8 zero8 = {0,0,0,0,0,0,0,0};

  for (int kc = 0; kc < FDIM; kc += 64) {
    f16x8 av  = aok ? *reinterpret_cast<const f16x8*>(ap + kc) : zero8;
    f16x8 bv0 = *reinterpret_cast<const f16x8*>(bp0 + kc);
    f16x8 bv1 = *reinterpret_cast<const f16x8*>(bp1 + kc);
    *reinterpret_cast<f16x8*>(&As[ar][ak])      = av;
    *reinterpret_cast<f16x8*>(&Bs[ar][ak])      = bv0;
    *reinterpret_cast<f16x8*>(&Bs[32 + ar][ak]) = bv1;
    __syncthreads();
    #pragma unroll
    for (int k2 = 0; k2 < 2; ++k2) {
      int ko = k2*32 + lg*8;
      f16x8 a  = *reinterpret_cast<const f16x8*>(&As[wr*16 + l15][ko]);
      f16x8 b0 = *reinterpret_cast<const f16x8*>(&Bs[wc*32 + l15][ko]);
      f16x8 b1 = *reinterpret_cast<const f16x8*>(&Bs[wc*32 + 16 + l15][ko]);
      acc0 = __builtin_amdgcn_mfma_f32_16x16x32_f16(a, b0, acc0, 0, 0, 0);
      acc1 = __builtin_amdgcn_mfma_f32_16x16x32_f16(a, b1, acc1, 0, 0, 0);
    }
    __syncthreads();
  }
  #pragma unroll
  for (int v = 0; v < 4; ++v) {
    int gr = r0 + wr*16 + lg*4 + v;
    if (gr < M) {
      int gc = c0 + wc*32 + l15;
      C[(size_t)gr*128 + gc]      = acc0[v];
      C[(size_t)gr*128 + gc + 16] = acc1[v];
    }
  }
}

// ---------------------------------------------------------------------------
// Fallback (ws too small): round-1 fused f32 kernel — known-correct.
// ---------------------------------------------------------------------------
__global__ __launch_bounds__(256) void ekp_stage1_fused(
    const float* __restrict__ q_pts, const float* __restrict__ s_pts,
    const int*   __restrict__ nbi,   const float* __restrict__ x,
    const float* __restrict__ q_lrf, const float* __restrict__ s_lrf,
    const float* __restrict__ weights, const float* __restrict__ kp,
    const float* __restrict__ mlp_w, const float* __restrict__ mlp_b,
    float* __restrict__ out)
{
  const int n = blockIdx.x;
  const int tid = threadIdx.x;

  __shared__ float sQ[36];
  __shared__ float sKP[45];
  __shared__ float sMW[36][32];
  __shared__ float sMB[32];
  __shared__ int   sIdx[32];
  __shared__ int   sShad[32];
  __shared__ float sNbr[32][3];
  __shared__ float sLrf[32][37];
  __shared__ float sW[4][15][32];
  __shared__ float sNbx[32][4][65];

  if (tid < 36) sQ[tid]  = q_lrf[(size_t)n*36 + tid];
  if (tid < 45) sKP[tid] = kp[tid];
  if (tid < 32) sMB[tid] = mlp_b[tid];
  for (int i = tid; i < 36*32; i += 256) sMW[i >> 5][i & 31] = mlp_w[i];
  if (tid < 32) {
    int idx = nbi[(size_t)n*Hh + tid];
    int sh = (idx >= NSn) ? 1 : 0;
    sShad[tid] = sh;
    sIdx[tid]  = sh ? 0 : idx;
  }
  __syncthreads();

  if (tid < 96) {
    int h = tid / 3, d = tid - h*3;
    float v = sShad[h] ? 0.f : s_pts[(size_t)sIdx[h]*3 + d];
    sNbr[h][d] = v - q_pts[(size_t)n*3 + d];
  }
  {
    int h = tid >> 3, j0 = tid & 7;
    const float* src = s_lrf + (size_t)sIdx[h]*36;
    float z = sShad[h] ? 0.f : 1.f;
    for (int j = j0; j < 36; j += 8) sLrf[h][j] = z * src[j];
  }
  for (int i = tid; i < Hh*128; i += 256) {
    int h = i >> 7, c = i & 127;
    float v = sShad[h] ? 0.f : x[(size_t)sIdx[h]*128 + c];
    sNbx[h][c >> 5][c & 31] = v;
  }
  __syncthreads();

  {
    int q = tid >> 6, l = tid & 63;
    int h = l & 31, kh = l >> 5;
    float a0 = 0.f, a1 = 0.f, a2 = 0.f;
    #pragma unroll
    for (int d = 0; d < 3; ++d) {
      float nd = sNbr[h][d];
      a0 += nd * sQ[q*9 + d*3 + 0];
      a1 += nd * sQ[q*9 + d*3 + 1];
      a2 += nd * sQ[q*9 + d*3 + 2];
    }
    float z = sShad[h] ? 0.f : 1.f;
    int k0 = kh * 8;
    int kend = k0 + (kh ? 7 : 8);
    for (int k = k0; k < kend; ++k) {
      float d0 = a0 - sKP[k*3+0];
      float d1 = a1 - sKP[k*3+1];
      float d2 = a2 - sKP[k*3+2];
      float wv2 = 1.f - sqrtf(d0*d0 + d1*d1 + d2*d2) * (1.0f/1.2f);
      sW[q][k][h] = z * fmaxf(wv2, 0.f);
    }
  }
  {
    int q = tid >> 6, l = tid & 63;
    int h = l & 31, mh = l >> 5;
    float fi[36];
    #pragma unroll
    for (int s = 0; s < 4; ++s)
      #pragma unroll
      for (int a = 0; a < 3; ++a)
        #pragma unroll
        for (int c = 0; c < 3; ++c) {
          float accv = 0.f;
          #pragma unroll
          for (int b = 0; b < 3; ++b)
            accv += sQ[q*9 + b*3 + a] * sLrf[h][s*9 + b*3 + c];
          fi[s*9 + a*3 + c] = accv;
        }
    float z = sShad[h] ? 0.f : 1.f;
    int m0 = mh * 16;
    for (int mm = 0; mm < 16; ++mm) {
      int m = m0 + mm;
      float accv = sMB[m];
      #pragma unroll
      for (int j = 0; j < 36; ++j) accv += fi[j] * sMW[j][m];
      sNbx[h][q][32 + m] = z * accv;
    }
  }
  __syncthreads();

  float acc[15];
  const int q = tid >> 6, cch = tid & 63;
  #pragma unroll
  for (int k = 0; k < 15; ++k) acc[k] = 0.f;
  for (int h = 0; h < Hh; ++h) {
    float v = sNbx[h][q][cch];
    #pragma unroll
    for (int k = 0; k < 15; ++k) acc[k] += sW[q][k][h] * v;
  }

  __shared__ float sWF[FDIM];
  __shared__ float sRed[2][128];
  #pragma unroll
  for (int k = 0; k < 15; ++k) sWF[k*256 + q*64 + cch] = acc[k];
  __syncthreads();
  int o = tid & 127, part = tid >> 7;
  const float* wp = weights + (size_t)part*1920*128 + o;
  const float* wfp = sWF + part*1920;
  float oa = 0.f;
  #pragma unroll 8
  for (int f = 0; f < 1920; ++f)
    oa += wfp[f] * wp[(size_t)f*128];
  sRed[part][o] = oa;
  __syncthreads();
  if (tid < 128) out[(size_t)n*128 + tid] = sRed[0][tid] + sRed[1][tid];
}

extern "C" void kernel_launch(void* const* d_in, const int* in_sizes, int n_in,
                              void* d_out, int out_size, void* d_ws, size_t ws_size,
                              hipStream_t stream) {
  const float* q_pts   = (const float*)d_in[0];
  const float* s_pts   = (const float*)d_in[1];
  const int*   nbi     = (const int*)  d_in[2];
  const float* x       = (const float*)d_in[3];
  const float* q_lrf   = (const float*)d_in[4];
  const float* s_lrf   = (const float*)d_in[5];
  const float* weights = (const float*)d_in[6];
  const float* kp      = (const float*)d_in[7];
  const float* mlp_w   = (const float*)d_in[8];
  const float* mlp_b   = (const float*)d_in[9];
  float* out = (float*)d_out;

  const size_t needBytes = ((size_t)NQn*FDIM + (size_t)128*FDIM) * sizeof(_Float16);
  if (ws_size >= needBytes) {
    _Float16* wf = (_Float16*)d_ws;
    _Float16* wt = wf + (size_t)NQn * FDIM;
    ekp_prep<<<128, 256, 0, stream>>>(weights, wt);
    ekp_stage1b<<<NQn, 256, 0, stream>>>(q_pts, s_pts, nbi, x, q_lrf, s_lrf,
                                         kp, mlp_w, mlp_b, wf);
    dim3 g2((NQn + 31) / 32, 2);
    ekp_gemm_f16<<<g2, 256, 0, stream>>>(wf, wt, out, NQn);
  } else {
    ekp_stage1_fused<<<NQn, 256, 0, stream>>>(q_pts, s_pts, nbi, x, q_lrf, s_lrf,
                                              weights, kp, mlp_w, mlp_b, out);
  }
}

// Round 3
// 189.482 us; speedup vs baseline: 2.7648x; 1.0770x over previous
//
#include <hip/hip_runtime.h>

#define NQn 10000
#define NSn 10000
#define Hh  32
#define FDIM 3840   // K(15) * 2*IN_CH(256)

typedef _Float16 f16x8 __attribute__((ext_vector_type(8)));
typedef float    f32x4 __attribute__((ext_vector_type(4)));

__device__ __forceinline__ unsigned pack2h(float a, float b) {
  union { _Float16 h; unsigned short u; } ua, ub;
  ua.h = (_Float16)a; ub.h = (_Float16)b;
  return (unsigned)ua.u | ((unsigned)ub.u << 16);
}

// ---------------------------------------------------------------------------
// Prep: Wt[n][k] = fp16(weights[k][n]) via LDS tile transpose (coalesced both sides)
// grid (120, 4), block 256
// ---------------------------------------------------------------------------
__global__ __launch_bounds__(256) void ekp_prep2(const float* __restrict__ w,
                                                 _Float16* __restrict__ wt) {
  __shared__ _Float16 t[32][34];
  const int k0 = blockIdx.x * 32, n0 = blockIdx.y * 32;
  const int c = threadIdx.x & 31, r0 = threadIdx.x >> 5;
  #pragma unroll
  for (int p = 0; p < 4; ++p) {
    int r = r0 + p*8;
    t[c][r] = (_Float16)w[(size_t)(k0 + r)*128 + n0 + c];
  }
  __syncthreads();
  #pragma unroll
  for (int p = 0; p < 4; ++p) {
    int r = r0 + p*8;
    wt[(size_t)(n0 + r)*FDIM + k0 + c] = t[r][c];
  }
}

// ---------------------------------------------------------------------------
// Stage 1: per-query block (4 waves, wave = q).
//  W2[q][sbc][m] = sum_a q_lrf[q,b,a]*mlp_w[(s,a,c),m]   (13.8K FMA/block)
//  feat[h][m]    = s_lrf_flat[h][sbc] @ W2                 (8 MFMAs/wave)
//  agg wf[k][c]  = w[k][h] @ nbx[h][c]                     (4 MFMAs/wave)
// ---------------------------------------------------------------------------
__global__ __launch_bounds__(256, 3) void ekp_stage1c(
    const float* __restrict__ q_pts, const float* __restrict__ s_pts,
    const int*   __restrict__ nbi,   const float* __restrict__ x,
    const float* __restrict__ q_lrf, const float* __restrict__ s_lrf,
    const float* __restrict__ kp,    const float* __restrict__ mlp_w,
    const float* __restrict__ mlp_b, _Float16* __restrict__ wf_out)
{
  const int n = blockIdx.x;
  const int tid = threadIdx.x;
  const int lane = tid & 63;
  const int wv = tid >> 6;          // wave id == q
  const int l15 = lane & 15, lg = lane >> 4;

  __shared__ float sQ[36];
  __shared__ float sMB[32];
  __shared__ int   sIdx[32];
  __shared__ float sZ[32];
  __shared__ float sNbr[32][3];
  __shared__ alignas(16) _Float16 sLrfA[32][72];    // [h][sbc], 144B rows
  __shared__ alignas(16) _Float16 sBw2[4][32][72];  // [q][m][sbc]
  __shared__ alignas(16) _Float16 sWb[4][16][40];   // [q][k][h]
  __shared__ alignas(16) _Float16 sNbxT[4][64][40]; // [q][c][h]

  // ---- phase 1: prelim loads + zero pads ----
  if (tid < 36) sQ[tid]  = q_lrf[(size_t)n*36 + tid];
  if (tid < 32) sMB[tid] = mlp_b[tid];
  if (tid < 32) {
    int idx = nbi[(size_t)n*Hh + tid];
    int sh = (idx >= NSn) ? 1 : 0;
    sZ[tid]   = sh ? 0.f : 1.f;
    sIdx[tid] = sh ? 0 : idx;
  }
  { unsigned* z = (unsigned*)&sBw2[0][0][0];
    for (int i = tid; i < 4608; i += 256) z[i] = 0u; }
  { unsigned* z = (unsigned*)&sLrfA[0][0];
    for (int i = tid; i < 1152; i += 256) z[i] = 0u; }
  __syncthreads();

  // ---- phase 2: gathers + W2 ----
  if (tid < 96) {
    int h = tid / 3, d = tid - h*3;
    sNbr[h][d] = sZ[h] * s_pts[(size_t)sIdx[h]*3 + d] - q_pts[(size_t)n*3 + d];
  }
  { // s_lrf gather -> fp16 A rows (flat sbc order == native s,b,c order)
    int h = tid >> 3, j0 = tid & 7;
    const float* src = s_lrf + (size_t)sIdx[h]*36;
    float z = sZ[h];
    for (int j = j0; j < 36; j += 8) sLrfA[h][j] = (_Float16)(z * src[j]);
  }
  // x gather -> sNbxT[q][c][h] (transposed fp16)
  #pragma unroll
  for (int it = 0; it < 4; ++it) {
    int i = tid + it*256;
    int cc = i & 127, h0 = (i >> 7) * 4;
    int q = cc >> 5, c = cc & 31;
    float v0 = sZ[h0+0] * x[(size_t)sIdx[h0+0]*128 + cc];
    float v1 = sZ[h0+1] * x[(size_t)sIdx[h0+1]*128 + cc];
    float v2 = sZ[h0+2] * x[(size_t)sIdx[h0+2]*128 + cc];
    float v3 = sZ[h0+3] * x[(size_t)sIdx[h0+3]*128 + cc];
    uint2 pk;
    pk.x = pack2h(v0, v1);
    pk.y = pack2h(v2, v3);
    *reinterpret_cast<uint2*>(&sNbxT[q][c][h0]) = pk;
  }
  // W2: 4608 outputs, 18 per thread (mlp_w read from global: 4.6KB, L1-hot)
  #pragma unroll
  for (int it = 0; it < 18; ++it) {
    int i = tid + it*256;
    int q = i / 1152, r = i - q*1152;
    int k = r >> 5, m = r & 31;
    int s = k / 9, bc = k - s*9, b = bc / 3, c = bc - b*3;
    int br = (s*9 + c)*32 + m;
    float acc = sQ[q*9 + b*3 + 0] * mlp_w[br]
              + sQ[q*9 + b*3 + 1] * mlp_w[br + 96]
              + sQ[q*9 + b*3 + 2] * mlp_w[br + 192];
    sBw2[q][m][k] = (_Float16)acc;
  }
  __syncthreads();

  // ---- phase 3: influence weights + feat MFMA ----
  {
    int h = lane & 31, kh = lane >> 5;
    float a0 = 0.f, a1 = 0.f, a2 = 0.f;
    #pragma unroll
    for (int d = 0; d < 3; ++d) {
      float nd = sNbr[h][d];
      a0 += nd * sQ[wv*9 + d*3 + 0];
      a1 += nd * sQ[wv*9 + d*3 + 1];
      a2 += nd * sQ[wv*9 + d*3 + 2];
    }
    float z = sZ[h];
    int k0 = kh * 8, kend = kh ? 15 : 8;
    for (int k = k0; k < kend; ++k) {
      float d0 = a0 - kp[k*3+0];
      float d1 = a1 - kp[k*3+1];
      float d2 = a2 - kp[k*3+2];
      float wgt = 1.f - sqrtf(d0*d0 + d1*d1 + d2*d2) * (1.0f/1.2f);
      sWb[wv][k][h] = (_Float16)(z * fmaxf(wgt, 0.f));
    }
    if (kh) sWb[wv][15][h] = (_Float16)0.f;
  }
  { // feat: [32h x 64k] @ [64k x 32m], K padded with zeros
    f32x4 fa[2][2];
    #pragma unroll
    for (int i = 0; i < 2; ++i)
      #pragma unroll
      for (int j = 0; j < 2; ++j) fa[i][j] = (f32x4){0.f,0.f,0.f,0.f};
    #pragma unroll
    for (int kc = 0; kc < 2; ++kc) {
      f16x8 af0 = *reinterpret_cast<const f16x8*>(&sLrfA[l15][kc*32 + lg*8]);
      f16x8 af1 = *reinterpret_cast<const f16x8*>(&sLrfA[16 + l15][kc*32 + lg*8]);
      f16x8 bf0 = *reinterpret_cast<const f16x8*>(&sBw2[wv][l15][kc*32 + lg*8]);
      f16x8 bf1 = *reinterpret_cast<const f16x8*>(&sBw2[wv][16 + l15][kc*32 + lg*8]);
      fa[0][0] = __builtin_amdgcn_mfma_f32_16x16x32_f16(af0, bf0, fa[0][0], 0, 0, 0);
      fa[0][1] = __builtin_amdgcn_mfma_f32_16x16x32_f16(af0, bf1, fa[0][1], 0, 0, 0);
      fa[1][0] = __builtin_amdgcn_mfma_f32_16x16x32_f16(af1, bf0, fa[1][0], 0, 0, 0);
      fa[1][1] = __builtin_amdgcn_mfma_f32_16x16x32_f16(af1, bf1, fa[1][1], 0, 0, 0);
    }
    // epilogue: +bias (masked via z), write transposed [32+m][h] as b64
    #pragma unroll
    for (int ht = 0; ht < 2; ++ht) {
      int hb = ht*16 + lg*4;
      float z0 = sZ[hb+0], z1 = sZ[hb+1], z2 = sZ[hb+2], z3 = sZ[hb+3];
      #pragma unroll
      for (int mt = 0; mt < 2; ++mt) {
        int m = mt*16 + l15;
        float bias = sMB[m];
        uint2 pk;
        pk.x = pack2h(fmaf(z0, bias, fa[ht][mt][0]), fmaf(z1, bias, fa[ht][mt][1]));
        pk.y = pack2h(fmaf(z2, bias, fa[ht][mt][2]), fmaf(z3, bias, fa[ht][mt][3]));
        *reinterpret_cast<uint2*>(&sNbxT[wv][32 + m][hb]) = pk;
      }
    }
  }
  __syncthreads();

  // ---- phase 4: aggregation MFMA + global store ----
  {
    f16x8 a = *reinterpret_cast<const f16x8*>(&sWb[wv][l15][lg*8]);
    #pragma unroll
    for (int ni = 0; ni < 4; ++ni) {
      f16x8 b = *reinterpret_cast<const f16x8*>(&sNbxT[wv][ni*16 + l15][lg*8]);
      f32x4 acc = {0.f, 0.f, 0.f, 0.f};
      acc = __builtin_amdgcn_mfma_f32_16x16x32_f16(a, b, acc, 0, 0, 0);
      int col = wv*64 + ni*16 + l15;
      #pragma unroll
      for (int v = 0; v < 4; ++v) {
        int k = lg*4 + v;
        if (k < 15)
          wf_out[(size_t)n*FDIM + k*256 + col] = (_Float16)acc[v];
      }
    }
  }
}

// ---------------------------------------------------------------------------
// Stage 2: out[10000,128] = wf[10000,3840] @ W[3840,128]
// BM=16, BN=128, BK=64; 625 blocks (exact), A read exactly once.
// ---------------------------------------------------------------------------
__global__ __launch_bounds__(256, 4) void ekp_gemm2(
    const _Float16* __restrict__ A,   // [M][FDIM]
    const _Float16* __restrict__ Bt,  // [128][FDIM]
    float* __restrict__ C)
{
  __shared__ alignas(16) _Float16 As[16][72];
  __shared__ alignas(16) _Float16 Bs[128][72];
  const int tid = threadIdx.x;
  const int lane = tid & 63;
  const int w = tid >> 6;
  const int r0 = blockIdx.x * 16;
  const int l15 = lane & 15, lg = lane >> 4;

  f32x4 acc0 = {0.f,0.f,0.f,0.f}, acc1 = {0.f,0.f,0.f,0.f};

  const int sr = tid >> 3;           // 0..31
  const int ak = (tid & 7) << 3;     // 0..56
  const _Float16* ap  = A + (size_t)(r0 + (sr & 15))*FDIM + ak;
  const _Float16* bp0 = Bt + (size_t)sr*FDIM + ak;

  for (int kc = 0; kc < FDIM; kc += 64) {
    if (sr < 16)
      *reinterpret_cast<f16x8*>(&As[sr][ak]) = *reinterpret_cast<const f16x8*>(ap + kc);
    #pragma unroll
    for (int p = 0; p < 4; ++p)
      *reinterpret_cast<f16x8*>(&Bs[p*32 + sr][ak]) =
        *reinterpret_cast<const f16x8*>(bp0 + (size_t)p*32*FDIM + kc);
    __syncthreads();
    #pragma unroll
    for (int k2 = 0; k2 < 2; ++k2) {
      int ko = k2*32 + lg*8;
      f16x8 a  = *reinterpret_cast<const f16x8*>(&As[l15][ko]);
      f16x8 b0 = *reinterpret_cast<const f16x8*>(&Bs[w*32 + l15][ko]);
      f16x8 b1 = *reinterpret_cast<const f16x8*>(&Bs[w*32 + 16 + l15][ko]);
      acc0 = __builtin_amdgcn_mfma_f32_16x16x32_f16(a, b0, acc0, 0, 0, 0);
      acc1 = __builtin_amdgcn_mfma_f32_16x16x32_f16(a, b1, acc1, 0, 0, 0);
    }
    __syncthreads();
  }
  #pragma unroll
  for (int v = 0; v < 4; ++v) {
    int gr = r0 + lg*4 + v;
    int gc = w*32 + l15;
    C[(size_t)gr*128 + gc]      = acc0[v];
    C[(size_t)gr*128 + gc + 16] = acc1[v];
  }
}

// ---------------------------------------------------------------------------
// Fallback (ws too small): round-1 fused f32 kernel — known-correct.
// ---------------------------------------------------------------------------
__global__ __launch_bounds__(256) void ekp_stage1_fused(
    const float* __restrict__ q_pts, const float* __restrict__ s_pts,
    const int*   __restrict__ nbi,   const float* __restrict__ x,
    const float* __restrict__ q_lrf, const float* __restrict__ s_lrf,
    const float* __restrict__ weights, const float* __restrict__ kp,
    const float* __restrict__ mlp_w, const float* __restrict__ mlp_b,
    float* __restrict__ out)
{
  const int n = blockIdx.x;
  const int tid = threadIdx.x;

  __shared__ float sQ[36];
  __shared__ float sKP[45];
  __shared__ float sMW[36][32];
  __shared__ float sMB[32];
  __shared__ int   sIdx[32];
  __shared__ int   sShad[32];
  __shared__ float sNbr[32][3];
  __shared__ float sLrf[32][37];
  __shared__ float sW[4][15][32];
  __shared__ float sNbx[32][4][65];

  if (tid < 36) sQ[tid]  = q_lrf[(size_t)n*36 + tid];
  if (tid < 45) sKP[tid] = kp[tid];
  if (tid < 32) sMB[tid] = mlp_b[tid];
  for (int i = tid; i < 36*32; i += 256) sMW[i >> 5][i & 31] = mlp_w[i];
  if (tid < 32) {
    int idx = nbi[(size_t)n*Hh + tid];
    int sh = (idx >= NSn) ? 1 : 0;
    sShad[tid] = sh;
    sIdx[tid]  = sh ? 0 : idx;
  }
  __syncthreads();

  if (tid < 96) {
    int h = tid / 3, d = tid - h*3;
    float v = sShad[h] ? 0.f : s_pts[(size_t)sIdx[h]*3 + d];
    sNbr[h][d] = v - q_pts[(size_t)n*3 + d];
  }
  {
    int h = tid >> 3, j0 = tid & 7;
    const float* src = s_lrf + (size_t)sIdx[h]*36;
    float z = sShad[h] ? 0.f : 1.f;
    for (int j = j0; j < 36; j += 8) sLrf[h][j] = z * src[j];
  }
  for (int i = tid; i < Hh*128; i += 256) {
    int h = i >> 7, c = i & 127;
    float v = sShad[h] ? 0.f : x[(size_t)sIdx[h]*128 + c];
    sNbx[h][c >> 5][c & 31] = v;
  }
  __syncthreads();

  {
    int q = tid >> 6, l = tid & 63;
    int h = l & 31, kh = l >> 5;
    float a0 = 0.f, a1 = 0.f, a2 = 0.f;
    #pragma unroll
    for (int d = 0; d < 3; ++d) {
      float nd = sNbr[h][d];
      a0 += nd * sQ[q*9 + d*3 + 0];
      a1 += nd * sQ[q*9 + d*3 + 1];
      a2 += nd * sQ[q*9 + d*3 + 2];
    }
    float z = sShad[h] ? 0.f : 1.f;
    int k0 = kh * 8;
    int kend = k0 + (kh ? 7 : 8);
    for (int k = k0; k < kend; ++k) {
      float d0 = a0 - sKP[k*3+0];
      float d1 = a1 - sKP[k*3+1];
      float d2 = a2 - sKP[k*3+2];
      float wv2 = 1.f - sqrtf(d0*d0 + d1*d1 + d2*d2) * (1.0f/1.2f);
      sW[q][k][h] = z * fmaxf(wv2, 0.f);
    }
  }
  {
    int q = tid >> 6, l = tid & 63;
    int h = l & 31, mh = l >> 5;
    float fi[36];
    #pragma unroll
    for (int s = 0; s < 4; ++s)
      #pragma unroll
      for (int a = 0; a < 3; ++a)
        #pragma unroll
        for (int c = 0; c < 3; ++c) {
          float accv = 0.f;
          #pragma unroll
          for (int b = 0; b < 3; ++b)
            accv += sQ[q*9 + b*3 + a] * sLrf[h][s*9 + b*3 + c];
          fi[s*9 + a*3 + c] = accv;
        }
    float z = sShad[h] ? 0.f : 1.f;
    int m0 = mh * 16;
    for (int mm = 0; mm < 16; ++mm) {
      int m = m0 + mm;
      float accv = sMB[m];
      #pragma unroll
      for (int j = 0; j < 36; ++j) accv += fi[j] * sMW[j][m];
      sNbx[h][q][32 + m] = z * accv;
    }
  }
  __syncthreads();

  float acc[15];
  const int q = tid >> 6, cch = tid & 63;
  #pragma unroll
  for (int k = 0; k < 15; ++k) acc[k] = 0.f;
  for (int h = 0; h < Hh; ++h) {
    float v = sNbx[h][q][cch];
    #pragma unroll
    for (int k = 0; k < 15; ++k) acc[k] += sW[q][k][h] * v;
  }

  __shared__ float sWF[FDIM];
  __shared__ float sRed[2][128];
  #pragma unroll
  for (int k = 0; k < 15; ++k) sWF[k*256 + q*64 + cch] = acc[k];
  __syncthreads();
  int o = tid & 127, part = tid >> 7;
  const float* wp = weights + (size_t)part*1920*128 + o;
  const float* wfp = sWF + part*1920;
  float oa = 0.f;
  #pragma unroll 8
  for (int f = 0; f < 1920; ++f)
    oa += wfp[f] * wp[(size_t)f*128];
  sRed[part][o] = oa;
  __syncthreads();
  if (tid < 128) out[(size_t)n*128 + tid] = sRed[0][tid] + sRed[1][tid];
}

extern "C" void kernel_launch(void* const* d_in, const int* in_sizes, int n_in,
                              void* d_out, int out_size, void* d_ws, size_t ws_size,
                              hipStream_t stream) {
  const float* q_pts   = (const float*)d_in[0];
  const float* s_pts   = (const float*)d_in[1];
  const int*   nbi     = (const int*)  d_in[2];
  const float* x       = (const float*)d_in[3];
  const float* q_lrf   = (const float*)d_in[4];
  const float* s_lrf   = (const float*)d_in[5];
  const float* weights = (const float*)d_in[6];
  const float* kp      = (const float*)d_in[7];
  const float* mlp_w   = (const float*)d_in[8];
  const float* mlp_b   = (const float*)d_in[9];
  float* out = (float*)d_out;

  const size_t needBytes = ((size_t)NQn*FDIM + (size_t)128*FDIM) * sizeof(_Float16);
  if (ws_size >= needBytes) {
    _Float16* wf = (_Float16*)d_ws;
    _Float16* wt = wf + (size_t)NQn * FDIM;
    dim3 gp(120, 4);
    ekp_prep2<<<gp, 256, 0, stream>>>(weights, wt);
    ekp_stage1c<<<NQn, 256, 0, stream>>>(q_pts, s_pts, nbi, x, q_lrf, s_lrf,
                                         kp, mlp_w, mlp_b, wf);
    ekp_gemm2<<<NQn/16, 256, 0, stream>>>(wf, wt, out);
  } else {
    ekp_stage1_fused<<<NQn, 256, 0, stream>>>(q_pts, s_pts, nbi, x, q_lrf, s_lrf,
                                              weights, kp, mlp_w, mlp_b, out);
  }
}

// Round 5
// 180.073 us; speedup vs baseline: 2.9093x; 1.0522x over previous
//
#include <hip/hip_runtime.h>

#define NQn 10000
#define NSn 10000
#define Hh  32
#define FDIM 3840   // K(15) * 2*IN_CH(256)

typedef _Float16 f16x8 __attribute__((ext_vector_type(8)));
typedef float    f32x4 __attribute__((ext_vector_type(4)));

__device__ __forceinline__ unsigned pack2h(float a, float b) {
  union { _Float16 h; unsigned short u; } ua, ub;
  ua.h = (_Float16)a; ub.h = (_Float16)b;
  return (unsigned)ua.u | ((unsigned)ub.u << 16);
}

// ---------------------------------------------------------------------------
// Prep: Wt[n][k] = fp16(weights[k][n]) via LDS tile transpose (coalesced both sides)
// grid (120, 4), block 256   [round-3 verbatim]
// ---------------------------------------------------------------------------
__global__ __launch_bounds__(256) void ekp_prep2(const float* __restrict__ w,
                                                 _Float16* __restrict__ wt) {
  __shared__ _Float16 t[32][34];
  const int k0 = blockIdx.x * 32, n0 = blockIdx.y * 32;
  const int c = threadIdx.x & 31, r0 = threadIdx.x >> 5;
  #pragma unroll
  for (int p = 0; p < 4; ++p) {
    int r = r0 + p*8;
    t[c][r] = (_Float16)w[(size_t)(k0 + r)*128 + n0 + c];
  }
  __syncthreads();
  #pragma unroll
  for (int p = 0; p < 4; ++p) {
    int r = r0 + p*8;
    wt[(size_t)(n0 + r)*FDIM + k0 + c] = t[r][c];
  }
}

// ---------------------------------------------------------------------------
// Stage 1 [round-3 verbatim, known-good]: per-query block (4 waves, wave = q).
//  W2[q][sbc][m] = sum_a q_lrf[q,b,a]*mlp_w[(s,a,c),m]
//  feat[h][m]    = s_lrf_flat[h][sbc] @ W2      (8 MFMAs/wave)
//  agg wf[k][c]  = w[k][h] @ nbx[h][c]          (4 MFMAs/wave)
// ---------------------------------------------------------------------------
__global__ __launch_bounds__(256, 3) void ekp_stage1c(
    const float* __restrict__ q_pts, const float* __restrict__ s_pts,
    const int*   __restrict__ nbi,   const float* __restrict__ x,
    const float* __restrict__ q_lrf, const float* __restrict__ s_lrf,
    const float* __restrict__ kp,    const float* __restrict__ mlp_w,
    const float* __restrict__ mlp_b, _Float16* __restrict__ wf_out)
{
  const int n = blockIdx.x;
  const int tid = threadIdx.x;
  const int lane = tid & 63;
  const int wv = tid >> 6;          // wave id == q
  const int l15 = lane & 15, lg = lane >> 4;

  __shared__ float sQ[36];
  __shared__ float sMB[32];
  __shared__ int   sIdx[32];
  __shared__ float sZ[32];
  __shared__ float sNbr[32][3];
  __shared__ alignas(16) _Float16 sLrfA[32][72];    // [h][sbc], 144B rows
  __shared__ alignas(16) _Float16 sBw2[4][32][72];  // [q][m][sbc]
  __shared__ alignas(16) _Float16 sWb[4][16][40];   // [q][k][h]
  __shared__ alignas(16) _Float16 sNbxT[4][64][40]; // [q][c][h]

  // ---- phase 1: prelim loads + zero pads ----
  if (tid < 36) sQ[tid]  = q_lrf[(size_t)n*36 + tid];
  if (tid < 32) sMB[tid] = mlp_b[tid];
  if (tid < 32) {
    int idx = nbi[(size_t)n*Hh + tid];
    int sh = (idx >= NSn) ? 1 : 0;
    sZ[tid]   = sh ? 0.f : 1.f;
    sIdx[tid] = sh ? 0 : idx;
  }
  { unsigned* z = (unsigned*)&sBw2[0][0][0];
    for (int i = tid; i < 4608; i += 256) z[i] = 0u; }
  { unsigned* z = (unsigned*)&sLrfA[0][0];
    for (int i = tid; i < 1152; i += 256) z[i] = 0u; }
  __syncthreads();

  // ---- phase 2: gathers + W2 ----
  if (tid < 96) {
    int h = tid / 3, d = tid - h*3;
    sNbr[h][d] = sZ[h] * s_pts[(size_t)sIdx[h]*3 + d] - q_pts[(size_t)n*3 + d];
  }
  { // s_lrf gather -> fp16 A rows (flat sbc order == native s,b,c order)
    int h = tid >> 3, j0 = tid & 7;
    const float* src = s_lrf + (size_t)sIdx[h]*36;
    float z = sZ[h];
    for (int j = j0; j < 36; j += 8) sLrfA[h][j] = (_Float16)(z * src[j]);
  }
  // x gather -> sNbxT[q][c][h] (transposed fp16)
  #pragma unroll
  for (int it = 0; it < 4; ++it) {
    int i = tid + it*256;
    int cc = i & 127, h0 = (i >> 7) * 4;
    int q = cc >> 5, c = cc & 31;
    float v0 = sZ[h0+0] * x[(size_t)sIdx[h0+0]*128 + cc];
    float v1 = sZ[h0+1] * x[(size_t)sIdx[h0+1]*128 + cc];
    float v2 = sZ[h0+2] * x[(size_t)sIdx[h0+2]*128 + cc];
    float v3 = sZ[h0+3] * x[(size_t)sIdx[h0+3]*128 + cc];
    uint2 pk;
    pk.x = pack2h(v0, v1);
    pk.y = pack2h(v2, v3);
    *reinterpret_cast<uint2*>(&sNbxT[q][c][h0]) = pk;
  }
  // W2: 4608 outputs, 18 per thread (mlp_w read from global: 4.6KB, L1-hot)
  #pragma unroll
  for (int it = 0; it < 18; ++it) {
    int i = tid + it*256;
    int q = i / 1152, r = i - q*1152;
    int k = r >> 5, m = r & 31;
    int s = k / 9, bc = k - s*9, b = bc / 3, c = bc - b*3;
    int br = (s*9 + c)*32 + m;
    float acc = sQ[q*9 + b*3 + 0] * mlp_w[br]
              + sQ[q*9 + b*3 + 1] * mlp_w[br + 96]
              + sQ[q*9 + b*3 + 2] * mlp_w[br + 192];
    sBw2[q][m][k] = (_Float16)acc;
  }
  __syncthreads();

  // ---- phase 3: influence weights + feat MFMA ----
  {
    int h = lane & 31, kh = lane >> 5;
    float a0 = 0.f, a1 = 0.f, a2 = 0.f;
    #pragma unroll
    for (int d = 0; d < 3; ++d) {
      float nd = sNbr[h][d];
      a0 += nd * sQ[wv*9 + d*3 + 0];
      a1 += nd * sQ[wv*9 + d*3 + 1];
      a2 += nd * sQ[wv*9 + d*3 + 2];
    }
    float z = sZ[h];
    int k0 = kh * 8, kend = kh ? 15 : 8;
    for (int k = k0; k < kend; ++k) {
      float d0 = a0 - kp[k*3+0];
      float d1 = a1 - kp[k*3+1];
      float d2 = a2 - kp[k*3+2];
      float wgt = 1.f - sqrtf(d0*d0 + d1*d1 + d2*d2) * (1.0f/1.2f);
      sWb[wv][k][h] = (_Float16)(z * fmaxf(wgt, 0.f));
    }
    if (kh) sWb[wv][15][h] = (_Float16)0.f;
  }
  { // feat: [32h x 64k] @ [64k x 32m], K padded with zeros
    f32x4 fa[2][2];
    #pragma unroll
    for (int i = 0; i < 2; ++i)
      #pragma unroll
      for (int j = 0; j < 2; ++j) fa[i][j] = (f32x4){0.f,0.f,0.f,0.f};
    #pragma unroll
    for (int kc = 0; kc < 2; ++kc) {
      f16x8 af0 = *reinterpret_cast<const f16x8*>(&sLrfA[l15][kc*32 + lg*8]);
      f16x8 af1 = *reinterpret_cast<const f16x8*>(&sLrfA[16 + l15][kc*32 + lg*8]);
      f16x8 bf0 = *reinterpret_cast<const f16x8*>(&sBw2[wv][l15][kc*32 + lg*8]);
      f16x8 bf1 = *reinterpret_cast<const f16x8*>(&sBw2[wv][16 + l15][kc*32 + lg*8]);
      fa[0][0] = __builtin_amdgcn_mfma_f32_16x16x32_f16(af0, bf0, fa[0][0], 0, 0, 0);
      fa[0][1] = __builtin_amdgcn_mfma_f32_16x16x32_f16(af0, bf1, fa[0][1], 0, 0, 0);
      fa[1][0] = __builtin_amdgcn_mfma_f32_16x16x32_f16(af1, bf0, fa[1][0], 0, 0, 0);
      fa[1][1] = __builtin_amdgcn_mfma_f32_16x16x32_f16(af1, bf1, fa[1][1], 0, 0, 0);
    }
    // epilogue: +bias (masked via z), write transposed [32+m][h] as b64
    #pragma unroll
    for (int ht = 0; ht < 2; ++ht) {
      int hb = ht*16 + lg*4;
      float z0 = sZ[hb+0], z1 = sZ[hb+1], z2 = sZ[hb+2], z3 = sZ[hb+3];
      #pragma unroll
      for (int mt = 0; mt < 2; ++mt) {
        int m = mt*16 + l15;
        float bias = sMB[m];
        uint2 pk;
        pk.x = pack2h(fmaf(z0, bias, fa[ht][mt][0]), fmaf(z1, bias, fa[ht][mt][1]));
        pk.y = pack2h(fmaf(z2, bias, fa[ht][mt][2]), fmaf(z3, bias, fa[ht][mt][3]));
        *reinterpret_cast<uint2*>(&sNbxT[wv][32 + m][hb]) = pk;
      }
    }
  }
  __syncthreads();

  // ---- phase 4: aggregation MFMA + global store ----
  {
    f16x8 a = *reinterpret_cast<const f16x8*>(&sWb[wv][l15][lg*8]);
    #pragma unroll
    for (int ni = 0; ni < 4; ++ni) {
      f16x8 b = *reinterpret_cast<const f16x8*>(&sNbxT[wv][ni*16 + l15][lg*8]);
      f32x4 acc = {0.f, 0.f, 0.f, 0.f};
      acc = __builtin_amdgcn_mfma_f32_16x16x32_f16(a, b, acc, 0, 0, 0);
      int col = wv*64 + ni*16 + l15;
      #pragma unroll
      for (int v = 0; v < 4; ++v) {
        int k = lg*4 + v;
        if (k < 15)
          wf_out[(size_t)n*FDIM + k*256 + col] = (_Float16)acc[v];
      }
    }
  }
}

// ---------------------------------------------------------------------------
// Stage 2 (NEW this round — the bisect target): out = wf @ W
// BM=32, BN=128, BK=64; grid 313. A read exactly once; B L2-traffic halved
// vs BM=16. Last block's A-rows 10000..10015 read into the adjacent wt
// region (finite fp16, never stored: gr<NQn guard).
// ---------------------------------------------------------------------------
__global__ __launch_bounds__(256, 4) void ekp_gemm3(
    const _Float16* __restrict__ A,   // [M][FDIM]
    const _Float16* __restrict__ Bt,  // [128][FDIM]
    float* __restrict__ C)
{
  __shared__ alignas(16) _Float16 As[32][72];
  __shared__ alignas(16) _Float16 Bs[128][72];
  const int tid = threadIdx.x, lane = tid & 63, w = tid >> 6;
  const int wr = w >> 1, wc = w & 1;
  const int r0 = blockIdx.x * 32;
  const int l15 = lane & 15, lg = lane >> 4;

  f32x4 acc[4];
  #pragma unroll
  for (int i = 0; i < 4; ++i) acc[i] = (f32x4){0.f,0.f,0.f,0.f};

  const int sr = tid >> 3;          // 0..31
  const int ak = (tid & 7) << 3;    // 0..56
  const _Float16* ap = A  + (size_t)(r0 + sr)*FDIM + ak;
  const _Float16* bp = Bt + (size_t)sr*FDIM + ak;

  for (int kc = 0; kc < FDIM; kc += 64) {
    *reinterpret_cast<f16x8*>(&As[sr][ak]) = *reinterpret_cast<const f16x8*>(ap + kc);
    #pragma unroll
    for (int p = 0; p < 4; ++p)
      *reinterpret_cast<f16x8*>(&Bs[p*32 + sr][ak]) =
        *reinterpret_cast<const f16x8*>(bp + (size_t)p*32*FDIM + kc);
    __syncthreads();
    #pragma unroll
    for (int k2 = 0; k2 < 2; ++k2) {
      const int ko = k2*32 + lg*8;
      f16x8 a = *reinterpret_cast<const f16x8*>(&As[wr*16 + l15][ko]);
      #pragma unroll
      for (int ni = 0; ni < 4; ++ni) {
        f16x8 b = *reinterpret_cast<const f16x8*>(&Bs[wc*64 + ni*16 + l15][ko]);
        acc[ni] = __builtin_amdgcn_mfma_f32_16x16x32_f16(a, b, acc[ni], 0, 0, 0);
      }
    }
    __syncthreads();
  }
  #pragma unroll
  for (int v = 0; v < 4; ++v) {
    int gr = r0 + wr*16 + lg*4 + v;
    if (gr < NQn) {
      #pragma unroll
      for (int ni = 0; ni < 4; ++ni)
        C[(size_t)gr*128 + wc*64 + ni*16 + l15] = acc[ni][v];
    }
  }
}

// ---------------------------------------------------------------------------
// Fallback (ws too small): round-1 fused f32 kernel — known-correct.
// ---------------------------------------------------------------------------
__global__ __launch_bounds__(256) void ekp_stage1_fused(
    const float* __restrict__ q_pts, const float* __restrict__ s_pts,
    const int*   __restrict__ nbi,   const float* __restrict__ x,
    const float* __restrict__ q_lrf, const float* __restrict__ s_lrf,
    const float* __restrict__ weights, const float* __restrict__ kp,
    const float* __restrict__ mlp_w, const float* __restrict__ mlp_b,
    float* __restrict__ out)
{
  const int n = blockIdx.x;
  const int tid = threadIdx.x;

  __shared__ float sQ[36];
  __shared__ float sKP[45];
  __shared__ float sMW[36][32];
  __shared__ float sMB[32];
  __shared__ int   sIdx[32];
  __shared__ int   sShad[32];
  __shared__ float sNbr[32][3];
  __shared__ float sLrf[32][37];
  __shared__ float sW[4][15][32];
  __shared__ float sNbx[32][4][65];

  if (tid < 36) sQ[tid]  = q_lrf[(size_t)n*36 + tid];
  if (tid < 45) sKP[tid] = kp[tid];
  if (tid < 32) sMB[tid] = mlp_b[tid];
  for (int i = tid; i < 36*32; i += 256) sMW[i >> 5][i & 31] = mlp_w[i];
  if (tid < 32) {
    int idx = nbi[(size_t)n*Hh + tid];
    int sh = (idx >= NSn) ? 1 : 0;
    sShad[tid] = sh;
    sIdx[tid]  = sh ? 0 : idx;
  }
  __syncthreads();

  if (tid < 96) {
    int h = tid / 3, d = tid - h*3;
    float v = sShad[h] ? 0.f : s_pts[(size_t)sIdx[h]*3 + d];
    sNbr[h][d] = v - q_pts[(size_t)n*3 + d];
  }
  {
    int h = tid >> 3, j0 = tid & 7;
    const float* src = s_lrf + (size_t)sIdx[h]*36;
    float z = sShad[h] ? 0.f : 1.f;
    for (int j = j0; j < 36; j += 8) sLrf[h][j] = z * src[j];
  }
  for (int i = tid; i < Hh*128; i += 256) {
    int h = i >> 7, c = i & 127;
    float v = sShad[h] ? 0.f : x[(size_t)sIdx[h]*128 + c];
    sNbx[h][c >> 5][c & 31] = v;
  }
  __syncthreads();

  {
    int q = tid >> 6, l = tid & 63;
    int h = l & 31, kh = l >> 5;
    float a0 = 0.f, a1 = 0.f, a2 = 0.f;
    #pragma unroll
    for (int d = 0; d < 3; ++d) {
      float nd = sNbr[h][d];
      a0 += nd * sQ[q*9 + d*3 + 0];
      a1 += nd * sQ[q*9 + d*3 + 1];
      a2 += nd * sQ[q*9 + d*3 + 2];
    }
    float z = sShad[h] ? 0.f : 1.f;
    int k0 = kh * 8;
    int kend = k0 + (kh ? 7 : 8);
    for (int k = k0; k < kend; ++k) {
      float d0 = a0 - sKP[k*3+0];
      float d1 = a1 - sKP[k*3+1];
      float d2 = a2 - sKP[k*3+2];
      float wv2 = 1.f - sqrtf(d0*d0 + d1*d1 + d2*d2) * (1.0f/1.2f);
      sW[q][k][h] = z * fmaxf(wv2, 0.f);
    }
  }
  {
    int q = tid >> 6, l = tid & 63;
    int h = l & 31, mh = l >> 5;
    float fi[36];
    #pragma unroll
    for (int s = 0; s < 4; ++s)
      #pragma unroll
      for (int a = 0; a < 3; ++a)
        #pragma unroll
        for (int c = 0; c < 3; ++c) {
          float accv = 0.f;
          #pragma unroll
          for (int b = 0; b < 3; ++b)
            accv += sQ[q*9 + b*3 + a] * sLrf[h][s*9 + b*3 + c];
          fi[s*9 + a*3 + c] = accv;
        }
    float z = sShad[h] ? 0.f : 1.f;
    int m0 = mh * 16;
    for (int mm = 0; mm < 16; ++mm) {
      int m = m0 + mm;
      float accv = sMB[m];
      #pragma unroll
      for (int j = 0; j < 36; ++j) accv += fi[j] * sMW[j][m];
      sNbx[h][q][32 + m] = z * accv;
    }
  }
  __syncthreads();

  float acc[15];
  const int q = tid >> 6, cch = tid & 63;
  #pragma unroll
  for (int k = 0; k < 15; ++k) acc[k] = 0.f;
  for (int h = 0; h < Hh; ++h) {
    float v = sNbx[h][q][cch];
    #pragma unroll
    for (int k = 0; k < 15; ++k) acc[k] += sW[q][k][h] * v;
  }

  __shared__ float sWF[FDIM];
  __shared__ float sRed[2][128];
  #pragma unroll
  for (int k = 0; k < 15; ++k) sWF[k*256 + q*64 + cch] = acc[k];
  __syncthreads();
  int o = tid & 127, part = tid >> 7;
  const float* wp = weights + (size_t)part*1920*128 + o;
  const float* wfp = sWF + part*1920;
  float oa = 0.f;
  #pragma unroll 8
  for (int f = 0; f < 1920; ++f)
    oa += wfp[f] * wp[(size_t)f*128];
  sRed[part][o] = oa;
  __syncthreads();
  if (tid < 128) out[(size_t)n*128 + tid] = sRed[0][tid] + sRed[1][tid];
}

extern "C" void kernel_launch(void* const* d_in, const int* in_sizes, int n_in,
                              void* d_out, int out_size, void* d_ws, size_t ws_size,
                              hipStream_t stream) {
  const float* q_pts   = (const float*)d_in[0];
  const float* s_pts   = (const float*)d_in[1];
  const int*   nbi     = (const int*)  d_in[2];
  const float* x       = (const float*)d_in[3];
  const float* q_lrf   = (const float*)d_in[4];
  const float* s_lrf   = (const float*)d_in[5];
  const float* weights = (const float*)d_in[6];
  const float* kp      = (const float*)d_in[7];
  const float* mlp_w   = (const float*)d_in[8];
  const float* mlp_b   = (const float*)d_in[9];
  float* out = (float*)d_out;

  const size_t nWf = (size_t)NQn * FDIM;
  const size_t nWt = (size_t)128 * FDIM;
  const size_t needBytes = (nWf + nWt) * sizeof(_Float16);
  if (ws_size >= needBytes) {
    _Float16* wf = (_Float16*)d_ws;
    _Float16* wt = wf + nWf;
    dim3 gp(120, 4);
    ekp_prep2<<<gp, 256, 0, stream>>>(weights, wt);
    ekp_stage1c<<<NQn, 256, 0, stream>>>(q_pts, s_pts, nbi, x, q_lrf, s_lrf,
                                         kp, mlp_w, mlp_b, wf);
    ekp_gemm3<<<(NQn + 31)/32, 256, 0, stream>>>(wf, wt, out);
  } else {
    ekp_stage1_fused<<<NQn, 256, 0, stream>>>(q_pts, s_pts, nbi, x, q_lrf, s_lrf,
                                              weights, kp, mlp_w, mlp_b, out);
  }
}

// Round 6
// 151.562 us; speedup vs baseline: 3.4566x; 1.1881x over previous
//
#include <hip/hip_runtime.h>

#define NQn 10000
#define NSn 10000
#define Hh  32
#define FDIM 3840   // K(15) * 2*IN_CH(256)

typedef _Float16 f16x8 __attribute__((ext_vector_type(8)));
typedef float    f32x4 __attribute__((ext_vector_type(4)));

__device__ __forceinline__ unsigned pack2h(float a, float b) {
  union { _Float16 h; unsigned short u; } ua, ub;
  ua.h = (_Float16)a; ub.h = (_Float16)b;
  return (unsigned)ua.u | ((unsigned)ub.u << 16);
}

// ---------------------------------------------------------------------------
// Prep (1105 blocks):
//   b <  625 : xh[i] = fp16(x[i])               (10000x128, vectorized)
//   else     : wt[n][k] = fp16(weights[k][n])   (LDS tile transpose, r3-verbatim)
// ---------------------------------------------------------------------------
__global__ __launch_bounds__(256) void ekp_prep3(
    const float* __restrict__ w, const float* __restrict__ x,
    _Float16* __restrict__ wt, _Float16* __restrict__ xh)
{
  const int b = blockIdx.x, tid = threadIdx.x;
  if (b < 625) {
    size_t base = (size_t)b*2048 + (size_t)tid*8;
    float4 a0 = *reinterpret_cast<const float4*>(x + base);
    float4 a1 = *reinterpret_cast<const float4*>(x + base + 4);
    uint4 o;
    o.x = pack2h(a0.x, a0.y); o.y = pack2h(a0.z, a0.w);
    o.z = pack2h(a1.x, a1.y); o.w = pack2h(a1.z, a1.w);
    *reinterpret_cast<uint4*>(xh + base) = o;
  } else {
    __shared__ _Float16 t[32][34];
    const int tt = b - 625;
    const int k0 = (tt % 120) * 32, n0 = (tt / 120) * 32;
    const int c = tid & 31, r0 = tid >> 5;
    #pragma unroll
    for (int p = 0; p < 4; ++p) {
      int r = r0 + p*8;
      t[c][r] = (_Float16)w[(size_t)(k0 + r)*128 + n0 + c];
    }
    __syncthreads();
    #pragma unroll
    for (int p = 0; p < 4; ++p) {
      int r = r0 + p*8;
      wt[(size_t)(n0 + r)*FDIM + k0 + c] = t[r][c];
    }
  }
}

// ---------------------------------------------------------------------------
// Stage 1e: r3's verified stage1c with ONE delta: the x-half of the
// aggregation B-operand is gathered per-lane from global fp16 xh in MFMA
// fragment layout (delta B), deleting the LDS x-transpose pass and 10KB of
// LDS (sNbxT[4][64][40] -> sFt[4][32][40]) => 4 blocks/CU.
// ---------------------------------------------------------------------------
__global__ __launch_bounds__(256, 4) void ekp_stage1e(
    const float* __restrict__ q_pts, const float* __restrict__ s_pts,
    const int*   __restrict__ nbi,   const unsigned short* __restrict__ xh,
    const float* __restrict__ q_lrf, const float* __restrict__ s_lrf,
    const float* __restrict__ kp,    const float* __restrict__ mlp_w,
    const float* __restrict__ mlp_b, _Float16* __restrict__ wf_out)
{
  const int n = blockIdx.x;
  const int tid = threadIdx.x;
  const int lane = tid & 63;
  const int wv = tid >> 6;          // wave id == q
  const int l15 = lane & 15, lg = lane >> 4;

  __shared__ float sQ[36];
  __shared__ float sMB[32];
  __shared__ int   sIdx[32];
  __shared__ float sZ[32];
  __shared__ float sNbr[32][3];
  __shared__ alignas(16) _Float16 sLrfA[32][72];    // [h][sbc], 144B rows
  __shared__ alignas(16) _Float16 sBw2[4][32][72];  // [q][m][sbc]
  __shared__ alignas(16) _Float16 sWb[4][16][40];   // [q][k][h]
  __shared__ alignas(16) _Float16 sFt[4][32][40];   // [q][m][h]  (lrf feat only)

  // ---- phase 1: prelim loads + zero pads ----
  if (tid < 36) sQ[tid]  = q_lrf[(size_t)n*36 + tid];
  if (tid < 32) sMB[tid] = mlp_b[tid];
  if (tid < 32) {
    int idx = nbi[(size_t)n*Hh + tid];
    int sh = (idx >= NSn) ? 1 : 0;
    sZ[tid]   = sh ? 0.f : 1.f;
    sIdx[tid] = sh ? 0 : idx;
  }
  { unsigned* z = (unsigned*)&sBw2[0][0][0];
    for (int i = tid; i < 4608; i += 256) z[i] = 0u; }
  { unsigned* z = (unsigned*)&sLrfA[0][0];
    for (int i = tid; i < 1152; i += 256) z[i] = 0u; }
  __syncthreads();

  // ---- phase 2: gathers + W2 ----
  if (tid < 96) {
    int h = tid / 3, d = tid - h*3;
    sNbr[h][d] = sZ[h] * s_pts[(size_t)sIdx[h]*3 + d] - q_pts[(size_t)n*3 + d];
  }
  { // s_lrf gather -> fp16 A rows (flat sbc order == native s,b,c order)
    int h = tid >> 3, j0 = tid & 7;
    const float* src = s_lrf + (size_t)sIdx[h]*36;
    float z = sZ[h];
    for (int j = j0; j < 36; j += 8) sLrfA[h][j] = (_Float16)(z * src[j]);
  }
  // W2: 4608 outputs, 18 per thread (mlp_w read from global: 4.6KB, L1-hot)
  #pragma unroll
  for (int it = 0; it < 18; ++it) {
    int i = tid + it*256;
    int q = i / 1152, r = i - q*1152;
    int k = r >> 5, m = r & 31;
    int s = k / 9, bc = k - s*9, b = bc / 3, c = bc - b*3;
    int br = (s*9 + c)*32 + m;
    float acc = sQ[q*9 + b*3 + 0] * mlp_w[br]
              + sQ[q*9 + b*3 + 1] * mlp_w[br + 96]
              + sQ[q*9 + b*3 + 2] * mlp_w[br + 192];
    sBw2[q][m][k] = (_Float16)acc;
  }
  __syncthreads();

  // ---- phase 3: influence weights + feat MFMA ----
  {
    int h = lane & 31, kh = lane >> 5;
    float a0 = 0.f, a1 = 0.f, a2 = 0.f;
    #pragma unroll
    for (int d = 0; d < 3; ++d) {
      float nd = sNbr[h][d];
      a0 += nd * sQ[wv*9 + d*3 + 0];
      a1 += nd * sQ[wv*9 + d*3 + 1];
      a2 += nd * sQ[wv*9 + d*3 + 2];
    }
    float z = sZ[h];
    int k0 = kh * 8, kend = kh ? 15 : 8;
    for (int k = k0; k < kend; ++k) {
      float d0 = a0 - kp[k*3+0];
      float d1 = a1 - kp[k*3+1];
      float d2 = a2 - kp[k*3+2];
      float wgt = 1.f - sqrtf(d0*d0 + d1*d1 + d2*d2) * (1.0f/1.2f);
      sWb[wv][k][h] = (_Float16)(z * fmaxf(wgt, 0.f));
    }
    if (kh) sWb[wv][15][h] = (_Float16)0.f;
  }
  { // feat: [32h x 64k] @ [64k x 32m], K padded with zeros
    f32x4 fa[2][2];
    #pragma unroll
    for (int i = 0; i < 2; ++i)
      #pragma unroll
      for (int j = 0; j < 2; ++j) fa[i][j] = (f32x4){0.f,0.f,0.f,0.f};
    #pragma unroll
    for (int kc = 0; kc < 2; ++kc) {
      f16x8 af0 = *reinterpret_cast<const f16x8*>(&sLrfA[l15][kc*32 + lg*8]);
      f16x8 af1 = *reinterpret_cast<const f16x8*>(&sLrfA[16 + l15][kc*32 + lg*8]);
      f16x8 bf0 = *reinterpret_cast<const f16x8*>(&sBw2[wv][l15][kc*32 + lg*8]);
      f16x8 bf1 = *reinterpret_cast<const f16x8*>(&sBw2[wv][16 + l15][kc*32 + lg*8]);
      fa[0][0] = __builtin_amdgcn_mfma_f32_16x16x32_f16(af0, bf0, fa[0][0], 0, 0, 0);
      fa[0][1] = __builtin_amdgcn_mfma_f32_16x16x32_f16(af0, bf1, fa[0][1], 0, 0, 0);
      fa[1][0] = __builtin_amdgcn_mfma_f32_16x16x32_f16(af1, bf0, fa[1][0], 0, 0, 0);
      fa[1][1] = __builtin_amdgcn_mfma_f32_16x16x32_f16(af1, bf1, fa[1][1], 0, 0, 0);
    }
    // epilogue: +bias (masked via z), write transposed [m][h] as uint2
    #pragma unroll
    for (int ht = 0; ht < 2; ++ht) {
      int hb = ht*16 + lg*4;
      float z0 = sZ[hb+0], z1 = sZ[hb+1], z2 = sZ[hb+2], z3 = sZ[hb+3];
      #pragma unroll
      for (int mt = 0; mt < 2; ++mt) {
        int m = mt*16 + l15;
        float bias = sMB[m];
        uint2 pk;
        pk.x = pack2h(fmaf(z0, bias, fa[ht][mt][0]), fmaf(z1, bias, fa[ht][mt][1]));
        pk.y = pack2h(fmaf(z2, bias, fa[ht][mt][2]), fmaf(z3, bias, fa[ht][mt][3]));
        *reinterpret_cast<uint2*>(&sFt[wv][m][hb]) = pk;
      }
    }
  }
  __syncthreads();

  // ---- phase 4: aggregation MFMA + global store ----
  {
    f16x8 a = *reinterpret_cast<const f16x8*>(&sWb[wv][l15][lg*8]);
    // x-half B-frags gathered from global fp16 xh (frag elem j <-> h=lg*8+j)
    union { unsigned u[4]; f16x8 v; } B0, B1;
    #pragma unroll
    for (int j = 0; j < 8; j += 2) {
      int h0 = lg*8 + j, h1 = h0 + 1;
      size_t r0 = (size_t)sIdx[h0]*128 + wv*32 + l15;
      size_t r1 = (size_t)sIdx[h1]*128 + wv*32 + l15;
      unsigned v00 = xh[r0],      v01 = xh[r1];
      unsigned v10 = xh[r0 + 16], v11 = xh[r1 + 16];
      if (sZ[h0] == 0.f) { v00 = 0; v10 = 0; }
      if (sZ[h1] == 0.f) { v01 = 0; v11 = 0; }
      B0.u[j >> 1] = v00 | (v01 << 16);
      B1.u[j >> 1] = v10 | (v11 << 16);
    }
    f16x8 b2 = *reinterpret_cast<const f16x8*>(&sFt[wv][l15][lg*8]);
    f16x8 b3 = *reinterpret_cast<const f16x8*>(&sFt[wv][16 + l15][lg*8]);

    _Float16* wp = wf_out + (size_t)n*FDIM + wv*64 + l15;
    f32x4 acc;
    acc = (f32x4){0.f,0.f,0.f,0.f};
    acc = __builtin_amdgcn_mfma_f32_16x16x32_f16(a, B0.v, acc, 0, 0, 0);
    #pragma unroll
    for (int v = 0; v < 4; ++v) { int k = lg*4 + v; if (k < 15) wp[k*256 +  0] = (_Float16)acc[v]; }
    acc = (f32x4){0.f,0.f,0.f,0.f};
    acc = __builtin_amdgcn_mfma_f32_16x16x32_f16(a, B1.v, acc, 0, 0, 0);
    #pragma unroll
    for (int v = 0; v < 4; ++v) { int k = lg*4 + v; if (k < 15) wp[k*256 + 16] = (_Float16)acc[v]; }
    acc = (f32x4){0.f,0.f,0.f,0.f};
    acc = __builtin_amdgcn_mfma_f32_16x16x32_f16(a, b2, acc, 0, 0, 0);
    #pragma unroll
    for (int v = 0; v < 4; ++v) { int k = lg*4 + v; if (k < 15) wp[k*256 + 32] = (_Float16)acc[v]; }
    acc = (f32x4){0.f,0.f,0.f,0.f};
    acc = __builtin_amdgcn_mfma_f32_16x16x32_f16(a, b3, acc, 0, 0, 0);
    #pragma unroll
    for (int v = 0; v < 4; ++v) { int k = lg*4 + v; if (k < 15) wp[k*256 + 48] = (_Float16)acc[v]; }
  }
}

// ---------------------------------------------------------------------------
// Stage 2 [r5-verbatim, verified]: out = wf @ W. BM=32, BN=128, grid 313.
// ---------------------------------------------------------------------------
__global__ __launch_bounds__(256, 4) void ekp_gemm3(
    const _Float16* __restrict__ A,   // [M][FDIM]
    const _Float16* __restrict__ Bt,  // [128][FDIM]
    float* __restrict__ C)
{
  __shared__ alignas(16) _Float16 As[32][72];
  __shared__ alignas(16) _Float16 Bs[128][72];
  const int tid = threadIdx.x, lane = tid & 63, w = tid >> 6;
  const int wr = w >> 1, wc = w & 1;
  const int r0 = blockIdx.x * 32;
  const int l15 = lane & 15, lg = lane >> 4;

  f32x4 acc[4];
  #pragma unroll
  for (int i = 0; i < 4; ++i) acc[i] = (f32x4){0.f,0.f,0.f,0.f};

  const int sr = tid >> 3;          // 0..31
  const int ak = (tid & 7) << 3;    // 0..56
  const _Float16* ap = A  + (size_t)(r0 + sr)*FDIM + ak;
  const _Float16* bp = Bt + (size_t)sr*FDIM + ak;

  for (int kc = 0; kc < FDIM; kc += 64) {
    *reinterpret_cast<f16x8*>(&As[sr][ak]) = *reinterpret_cast<const f16x8*>(ap + kc);
    #pragma unroll
    for (int p = 0; p < 4; ++p)
      *reinterpret_cast<f16x8*>(&Bs[p*32 + sr][ak]) =
        *reinterpret_cast<const f16x8*>(bp + (size_t)p*32*FDIM + kc);
    __syncthreads();
    #pragma unroll
    for (int k2 = 0; k2 < 2; ++k2) {
      const int ko = k2*32 + lg*8;
      f16x8 a = *reinterpret_cast<const f16x8*>(&As[wr*16 + l15][ko]);
      #pragma unroll
      for (int ni = 0; ni < 4; ++ni) {
        f16x8 b = *reinterpret_cast<const f16x8*>(&Bs[wc*64 + ni*16 + l15][ko]);
        acc[ni] = __builtin_amdgcn_mfma_f32_16x16x32_f16(a, b, acc[ni], 0, 0, 0);
      }
    }
    __syncthreads();
  }
  #pragma unroll
  for (int v = 0; v < 4; ++v) {
    int gr = r0 + wr*16 + lg*4 + v;
    if (gr < NQn) {
      #pragma unroll
      for (int ni = 0; ni < 4; ++ni)
        C[(size_t)gr*128 + wc*64 + ni*16 + l15] = acc[ni][v];
    }
  }
}

// ---------------------------------------------------------------------------
// Fallback (ws too small): round-1 fused f32 kernel — known-correct.
// ---------------------------------------------------------------------------
__global__ __launch_bounds__(256) void ekp_stage1_fused(
    const float* __restrict__ q_pts, const float* __restrict__ s_pts,
    const int*   __restrict__ nbi,   const float* __restrict__ x,
    const float* __restrict__ q_lrf, const float* __restrict__ s_lrf,
    const float* __restrict__ weights, const float* __restrict__ kp,
    const float* __restrict__ mlp_w, const float* __restrict__ mlp_b,
    float* __restrict__ out)
{
  const int n = blockIdx.x;
  const int tid = threadIdx.x;

  __shared__ float sQ[36];
  __shared__ float sKP[45];
  __shared__ float sMW[36][32];
  __shared__ float sMB[32];
  __shared__ int   sIdx[32];
  __shared__ int   sShad[32];
  __shared__ float sNbr[32][3];
  __shared__ float sLrf[32][37];
  __shared__ float sW[4][15][32];
  __shared__ float sNbx[32][4][65];

  if (tid < 36) sQ[tid]  = q_lrf[(size_t)n*36 + tid];
  if (tid < 45) sKP[tid] = kp[tid];
  if (tid < 32) sMB[tid] = mlp_b[tid];
  for (int i = tid; i < 36*32; i += 256) sMW[i >> 5][i & 31] = mlp_w[i];
  if (tid < 32) {
    int idx = nbi[(size_t)n*Hh + tid];
    int sh = (idx >= NSn) ? 1 : 0;
    sShad[tid] = sh;
    sIdx[tid]  = sh ? 0 : idx;
  }
  __syncthreads();

  if (tid < 96) {
    int h = tid / 3, d = tid - h*3;
    float v = sShad[h] ? 0.f : s_pts[(size_t)sIdx[h]*3 + d];
    sNbr[h][d] = v - q_pts[(size_t)n*3 + d];
  }
  {
    int h = tid >> 3, j0 = tid & 7;
    const float* src = s_lrf + (size_t)sIdx[h]*36;
    float z = sShad[h] ? 0.f : 1.f;
    for (int j = j0; j < 36; j += 8) sLrf[h][j] = z * src[j];
  }
  for (int i = tid; i < Hh*128; i += 256) {
    int h = i >> 7, c = i & 127;
    float v = sShad[h] ? 0.f : x[(size_t)sIdx[h]*128 + c];
    sNbx[h][c >> 5][c & 31] = v;
  }
  __syncthreads();

  {
    int q = tid >> 6, l = tid & 63;
    int h = l & 31, kh = l >> 5;
    float a0 = 0.f, a1 = 0.f, a2 = 0.f;
    #pragma unroll
    for (int d = 0; d < 3; ++d) {
      float nd = sNbr[h][d];
      a0 += nd * sQ[q*9 + d*3 + 0];
      a1 += nd * sQ[q*9 + d*3 + 1];
      a2 += nd * sQ[q*9 + d*3 + 2];
    }
    float z = sShad[h] ? 0.f : 1.f;
    int k0 = kh * 8;
    int kend = k0 + (kh ? 7 : 8);
    for (int k = k0; k < kend; ++k) {
      float d0 = a0 - sKP[k*3+0];
      float d1 = a1 - sKP[k*3+1];
      float d2 = a2 - sKP[k*3+2];
      float wv2 = 1.f - sqrtf(d0*d0 + d1*d1 + d2*d2) * (1.0f/1.2f);
      sW[q][k][h] = z * fmaxf(wv2, 0.f);
    }
  }
  {
    int q = tid >> 6, l = tid & 63;
    int h = l & 31, mh = l >> 5;
    float fi[36];
    #pragma unroll
    for (int s = 0; s < 4; ++s)
      #pragma unroll
      for (int a = 0; a < 3; ++a)
        #pragma unroll
        for (int c = 0; c < 3; ++c) {
          float accv = 0.f;
          #pragma unroll
          for (int b = 0; b < 3; ++b)
            accv += sQ[q*9 + b*3 + a] * sLrf[h][s*9 + b*3 + c];
          fi[s*9 + a*3 + c] = accv;
        }
    float z = sShad[h] ? 0.f : 1.f;
    int m0 = mh * 16;
    for (int mm = 0; mm < 16; ++mm) {
      int m = m0 + mm;
      float accv = sMB[m];
      #pragma unroll
      for (int j = 0; j < 36; ++j) accv += fi[j] * sMW[j][m];
      sNbx[h][q][32 + m] = z * accv;
    }
  }
  __syncthreads();

  float acc[15];
  const int q = tid >> 6, cch = tid & 63;
  #pragma unroll
  for (int k = 0; k < 15; ++k) acc[k] = 0.f;
  for (int h = 0; h < Hh; ++h) {
    float v = sNbx[h][q][cch];
    #pragma unroll
    for (int k = 0; k < 15; ++k) acc[k] += sW[q][k][h] * v;
  }

  __shared__ float sWF[FDIM];
  __shared__ float sRed[2][128];
  #pragma unroll
  for (int k = 0; k < 15; ++k) sWF[k*256 + q*64 + cch] = acc[k];
  __syncthreads();
  int o = tid & 127, part = tid >> 7;
  const float* wp = weights + (size_t)part*1920*128 + o;
  const float* wfp = sWF + part*1920;
  float oa = 0.f;
  #pragma unroll 8
  for (int f = 0; f < 1920; ++f)
    oa += wfp[f] * wp[(size_t)f*128];
  sRed[part][o] = oa;
  __syncthreads();
  if (tid < 128) out[(size_t)n*128 + tid] = sRed[0][tid] + sRed[1][tid];
}

extern "C" void kernel_launch(void* const* d_in, const int* in_sizes, int n_in,
                              void* d_out, int out_size, void* d_ws, size_t ws_size,
                              hipStream_t stream) {
  const float* q_pts   = (const float*)d_in[0];
  const float* s_pts   = (const float*)d_in[1];
  const int*   nbi     = (const int*)  d_in[2];
  const float* x       = (const float*)d_in[3];
  const float* q_lrf   = (const float*)d_in[4];
  const float* s_lrf   = (const float*)d_in[5];
  const float* weights = (const float*)d_in[6];
  const float* kp      = (const float*)d_in[7];
  const float* mlp_w   = (const float*)d_in[8];
  const float* mlp_b   = (const float*)d_in[9];
  float* out = (float*)d_out;

  const size_t nWf = (size_t)NQn * FDIM;
  const size_t nWt = (size_t)128 * FDIM;
  const size_t nXh = (size_t)NSn * 128;
  const size_t needBytes = (nWf + nWt + nXh) * sizeof(_Float16);
  if (ws_size >= needBytes) {
    _Float16* wf = (_Float16*)d_ws;
    _Float16* wt = wf + nWf;
    _Float16* xh = wt + nWt;
    ekp_prep3<<<1105, 256, 0, stream>>>(weights, x, wt, xh);
    ekp_stage1e<<<NQn, 256, 0, stream>>>(q_pts, s_pts, nbi,
                                         (const unsigned short*)xh,
                                         q_lrf, s_lrf, kp, mlp_w, mlp_b, wf);
    ekp_gemm3<<<(NQn + 31)/32, 256, 0, stream>>>(wf, wt, out);
  } else {
    ekp_stage1_fused<<<NQn, 256, 0, stream>>>(q_pts, s_pts, nbi, x, q_lrf, s_lrf,
                                              weights, kp, mlp_w, mlp_b, out);
  }
}

// Round 9
// 144.021 us; speedup vs baseline: 3.6376x; 1.0524x over previous
//
#include <hip/hip_runtime.h>

#define NQn 10000
#define NSn 10000
#define Hh  32
#define FDIM 3840   // K(15) * 2*IN_CH(256)

typedef _Float16 f16x8 __attribute__((ext_vector_type(8)));
typedef float    f32x4 __attribute__((ext_vector_type(4)));

__device__ __forceinline__ unsigned pack2h(float a, float b) {
  union { _Float16 h; unsigned short u; } ua, ub;
  ua.h = (_Float16)a; ub.h = (_Float16)b;
  return (unsigned)ua.u | ((unsigned)ub.u << 16);
}

// ---------------------------------------------------------------------------
// Prep (1106 blocks):
//   b <  625 : xh[i] = fp16(x[i])               (10000x128, vectorized)
//   b == 625 : xh row NSn = 0                   (shadow zero-row)
//   else     : wt[n][k] = fp16(weights[k][n])   (LDS tile transpose)
// ---------------------------------------------------------------------------
__global__ __launch_bounds__(256) void ekp_prep5(
    const float* __restrict__ w, const float* __restrict__ x,
    _Float16* __restrict__ wt, _Float16* __restrict__ xh)
{
  const int b = blockIdx.x, tid = threadIdx.x;
  if (b < 625) {
    size_t base = (size_t)b*2048 + (size_t)tid*8;
    float4 a0 = *reinterpret_cast<const float4*>(x + base);
    float4 a1 = *reinterpret_cast<const float4*>(x + base + 4);
    uint4 o;
    o.x = pack2h(a0.x, a0.y); o.y = pack2h(a0.z, a0.w);
    o.z = pack2h(a1.x, a1.y); o.w = pack2h(a1.z, a1.w);
    *reinterpret_cast<uint4*>(xh + base) = o;
  } else if (b == 625) {
    if (tid < 64)
      reinterpret_cast<unsigned*>(xh + (size_t)NSn*128)[tid] = 0u;
  } else {
    __shared__ _Float16 t[32][34];
    const int tt = b - 626;
    const int k0 = (tt % 120) * 32, n0 = (tt / 120) * 32;
    const int c = tid & 31, r0 = tid >> 5;
    #pragma unroll
    for (int p = 0; p < 4; ++p) {
      int r = r0 + p*8;
      t[c][r] = (_Float16)w[(size_t)(k0 + r)*128 + n0 + c];
    }
    __syncthreads();
    #pragma unroll
    for (int p = 0; p < 4; ++p) {
      int r = r0 + p*8;
      wt[(size_t)(n0 + r)*FDIM + k0 + c] = t[r][c];
    }
  }
}

// ---------------------------------------------------------------------------
// Stage 1h: r6's verified stage1e + (1) unclamped sIdxX into zero-padded xh
// (drops phase-4 mask cndmasks), (2) float4 s_lrf gather. W2 pass, pads,
// MFMAs, epilogue: r6 verbatim.
// ---------------------------------------------------------------------------
__global__ __launch_bounds__(256, 4) void ekp_stage1h(
    const float* __restrict__ q_pts, const float* __restrict__ s_pts,
    const int*   __restrict__ nbi,   const unsigned short* __restrict__ xh,
    const float* __restrict__ q_lrf, const float* __restrict__ s_lrf,
    const float* __restrict__ kp,    const float* __restrict__ mlp_w,
    const float* __restrict__ mlp_b, _Float16* __restrict__ wf_out)
{
  const int n = blockIdx.x;
  const int tid = threadIdx.x;
  const int lane = tid & 63;
  const int wv = tid >> 6;          // wave id == q
  const int l15 = lane & 15, lg = lane >> 4;

  __shared__ float sQ[36];
  __shared__ float sMB[32];
  __shared__ int   sIdx[32];        // clamped (for s_pts/s_lrf)
  __shared__ int   sIdxX[32];       // unclamped (xh has zero row at NSn)
  __shared__ float sZ[32];
  __shared__ float sNbr[32][3];
  __shared__ alignas(16) _Float16 sLrfA[32][72];    // [h][sbc], 144B rows
  __shared__ alignas(16) _Float16 sBw2[4][32][72];  // [q][m][sbc]
  __shared__ alignas(16) _Float16 sWb[4][16][40];   // [q][k][h]
  __shared__ alignas(16) _Float16 sFt[4][32][40];   // [q][m][h]

  // ---- phase 1: prelim loads + zero pads [r6 verbatim zeroing] ----
  if (tid < 36) sQ[tid]  = q_lrf[(size_t)n*36 + tid];
  if (tid < 32) sMB[tid] = mlp_b[tid];
  if (tid < 32) {
    int idx = nbi[(size_t)n*Hh + tid];
    int sh = (idx >= NSn) ? 1 : 0;
    sZ[tid]    = sh ? 0.f : 1.f;
    sIdx[tid]  = sh ? 0 : idx;
    sIdxX[tid] = idx;              // idx in [0, NSn]; row NSn of xh is zero
  }
  { unsigned* z = (unsigned*)&sBw2[0][0][0];
    for (int i = tid; i < 4608; i += 256) z[i] = 0u; }
  { unsigned* z = (unsigned*)&sLrfA[0][0];
    for (int i = tid; i < 1152; i += 256) z[i] = 0u; }
  __syncthreads();

  // ---- phase 2: gathers + W2 ----
  if (tid < 96) {
    int h = tid / 3, d = tid - h*3;
    sNbr[h][d] = sZ[h] * s_pts[(size_t)sIdx[h]*3 + d] - q_pts[(size_t)n*3 + d];
  }
  // s_lrf gather, float4-vectorized: 288 float4 (row = f4i/9, c4 = f4i%9)
  for (int f4i = tid; f4i < 288; f4i += 256) {
    int row = f4i / 9, c4 = f4i - row*9;
    float4 v = *reinterpret_cast<const float4*>(
        s_lrf + (size_t)sIdx[row]*36 + c4*4);
    float z = sZ[row];
    uint2 pk;
    pk.x = pack2h(z*v.x, z*v.y);
    pk.y = pack2h(z*v.z, z*v.w);
    *reinterpret_cast<uint2*>(&sLrfA[row][c4*4]) = pk;
  }
  // W2: 4608 outputs, 18 per thread [r6 verbatim]
  #pragma unroll
  for (int it = 0; it < 18; ++it) {
    int i = tid + it*256;
    int q = i / 1152, r = i - q*1152;
    int k = r >> 5, m = r & 31;
    int s = k / 9, bc = k - s*9, b = bc / 3, c = bc - b*3;
    int br = (s*9 + c)*32 + m;
    float acc = sQ[q*9 + b*3 + 0] * mlp_w[br]
              + sQ[q*9 + b*3 + 1] * mlp_w[br + 96]
              + sQ[q*9 + b*3 + 2] * mlp_w[br + 192];
    sBw2[q][m][k] = (_Float16)acc;
  }
  __syncthreads();

  // ---- phase 3: influence weights + feat MFMA [r6 verbatim] ----
  {
    int h = lane & 31, kh = lane >> 5;
    float a0 = 0.f, a1 = 0.f, a2 = 0.f;
    #pragma unroll
    for (int d = 0; d < 3; ++d) {
      float nd = sNbr[h][d];
      a0 += nd * sQ[wv*9 + d*3 + 0];
      a1 += nd * sQ[wv*9 + d*3 + 1];
      a2 += nd * sQ[wv*9 + d*3 + 2];
    }
    float z = sZ[h];
    int k0 = kh * 8, kend = kh ? 15 : 8;
    for (int k = k0; k < kend; ++k) {
      float d0 = a0 - kp[k*3+0];
      float d1 = a1 - kp[k*3+1];
      float d2 = a2 - kp[k*3+2];
      float wgt = 1.f - sqrtf(d0*d0 + d1*d1 + d2*d2) * (1.0f/1.2f);
      sWb[wv][k][h] = (_Float16)(z * fmaxf(wgt, 0.f));
    }
    if (kh) sWb[wv][15][h] = (_Float16)0.f;
  }
  { // feat: [32h x 64k] @ [64k x 32m], K padded with zeros
    f32x4 fa[2][2];
    #pragma unroll
    for (int i = 0; i < 2; ++i)
      #pragma unroll
      for (int j = 0; j < 2; ++j) fa[i][j] = (f32x4){0.f,0.f,0.f,0.f};
    #pragma unroll
    for (int kc = 0; kc < 2; ++kc) {
      f16x8 af0 = *reinterpret_cast<const f16x8*>(&sLrfA[l15][kc*32 + lg*8]);
      f16x8 af1 = *reinterpret_cast<const f16x8*>(&sLrfA[16 + l15][kc*32 + lg*8]);
      f16x8 bf0 = *reinterpret_cast<const f16x8*>(&sBw2[wv][l15][kc*32 + lg*8]);
      f16x8 bf1 = *reinterpret_cast<const f16x8*>(&sBw2[wv][16 + l15][kc*32 + lg*8]);
      fa[0][0] = __builtin_amdgcn_mfma_f32_16x16x32_f16(af0, bf0, fa[0][0], 0, 0, 0);
      fa[0][1] = __builtin_amdgcn_mfma_f32_16x16x32_f16(af0, bf1, fa[0][1], 0, 0, 0);
      fa[1][0] = __builtin_amdgcn_mfma_f32_16x16x32_f16(af1, bf0, fa[1][0], 0, 0, 0);
      fa[1][1] = __builtin_amdgcn_mfma_f32_16x16x32_f16(af1, bf1, fa[1][1], 0, 0, 0);
    }
    // epilogue: +bias (masked via z), write transposed [m][h] as uint2
    #pragma unroll
    for (int ht = 0; ht < 2; ++ht) {
      int hb = ht*16 + lg*4;
      float z0 = sZ[hb+0], z1 = sZ[hb+1], z2 = sZ[hb+2], z3 = sZ[hb+3];
      #pragma unroll
      for (int mt = 0; mt < 2; ++mt) {
        int m = mt*16 + l15;
        float bias = sMB[m];
        uint2 pk;
        pk.x = pack2h(fmaf(z0, bias, fa[ht][mt][0]), fmaf(z1, bias, fa[ht][mt][1]));
        pk.y = pack2h(fmaf(z2, bias, fa[ht][mt][2]), fmaf(z3, bias, fa[ht][mt][3]));
        *reinterpret_cast<uint2*>(&sFt[wv][m][hb]) = pk;
      }
    }
  }
  __syncthreads();

  // ---- phase 4: aggregation MFMA + global store ----
  {
    f16x8 a = *reinterpret_cast<const f16x8*>(&sWb[wv][l15][lg*8]);
    // x-half B-frags from xh; shadow neighbors read the zero row (no masks)
    union { unsigned u[4]; f16x8 v; } B0, B1;
    #pragma unroll
    for (int j = 0; j < 8; j += 2) {
      int h0 = lg*8 + j, h1 = h0 + 1;
      size_t r0 = (size_t)sIdxX[h0]*128 + wv*32 + l15;
      size_t r1 = (size_t)sIdxX[h1]*128 + wv*32 + l15;
      B0.u[j >> 1] = (unsigned)xh[r0]      | ((unsigned)xh[r1]      << 16);
      B1.u[j >> 1] = (unsigned)xh[r0 + 16] | ((unsigned)xh[r1 + 16] << 16);
    }
    f16x8 b2 = *reinterpret_cast<const f16x8*>(&sFt[wv][l15][lg*8]);
    f16x8 b3 = *reinterpret_cast<const f16x8*>(&sFt[wv][16 + l15][lg*8]);

    _Float16* wp = wf_out + (size_t)n*FDIM + wv*64 + l15;
    f32x4 acc;
    acc = (f32x4){0.f,0.f,0.f,0.f};
    acc = __builtin_amdgcn_mfma_f32_16x16x32_f16(a, B0.v, acc, 0, 0, 0);
    #pragma unroll
    for (int v = 0; v < 4; ++v) { int k = lg*4 + v; if (k < 15) wp[k*256 +  0] = (_Float16)acc[v]; }
    acc = (f32x4){0.f,0.f,0.f,0.f};
    acc = __builtin_amdgcn_mfma_f32_16x16x32_f16(a, B1.v, acc, 0, 0, 0);
    #pragma unroll
    for (int v = 0; v < 4; ++v) { int k = lg*4 + v; if (k < 15) wp[k*256 + 16] = (_Float16)acc[v]; }
    acc = (f32x4){0.f,0.f,0.f,0.f};
    acc = __builtin_amdgcn_mfma_f32_16x16x32_f16(a, b2, acc, 0, 0, 0);
    #pragma unroll
    for (int v = 0; v < 4; ++v) { int k = lg*4 + v; if (k < 15) wp[k*256 + 32] = (_Float16)acc[v]; }
    acc = (f32x4){0.f,0.f,0.f,0.f};
    acc = __builtin_amdgcn_mfma_f32_16x16x32_f16(a, b3, acc, 0, 0, 0);
    #pragma unroll
    for (int v = 0; v < 4; ++v) { int k = lg*4 + v; if (k < 15) wp[k*256 + 48] = (_Float16)acc[v]; }
  }
}

// ---------------------------------------------------------------------------
// Stage 2 [verified, r6 verbatim]: out = wf @ W. BM=32, BN=128, grid 313.
// ---------------------------------------------------------------------------
__global__ __launch_bounds__(256, 4) void ekp_gemm3(
    const _Float16* __restrict__ A,   // [M][FDIM]
    const _Float16* __restrict__ Bt,  // [128][FDIM]
    float* __restrict__ C)
{
  __shared__ alignas(16) _Float16 As[32][72];
  __shared__ alignas(16) _Float16 Bs[128][72];
  const int tid = threadIdx.x, lane = tid & 63, w = tid >> 6;
  const int wr = w >> 1, wc = w & 1;
  const int r0 = blockIdx.x * 32;
  const int l15 = lane & 15, lg = lane >> 4;

  f32x4 acc[4];
  #pragma unroll
  for (int i = 0; i < 4; ++i) acc[i] = (f32x4){0.f,0.f,0.f,0.f};

  const int sr = tid >> 3;          // 0..31
  const int ak = (tid & 7) << 3;    // 0..56
  const _Float16* ap = A  + (size_t)(r0 + sr)*FDIM + ak;
  const _Float16* bp = Bt + (size_t)sr*FDIM + ak;

  for (int kc = 0; kc < FDIM; kc += 64) {
    *reinterpret_cast<f16x8*>(&As[sr][ak]) = *reinterpret_cast<const f16x8*>(ap + kc);
    #pragma unroll
    for (int p = 0; p < 4; ++p)
      *reinterpret_cast<f16x8*>(&Bs[p*32 + sr][ak]) =
        *reinterpret_cast<const f16x8*>(bp + (size_t)p*32*FDIM + kc);
    __syncthreads();
    #pragma unroll
    for (int k2 = 0; k2 < 2; ++k2) {
      const int ko = k2*32 + lg*8;
      f16x8 a = *reinterpret_cast<const f16x8*>(&As[wr*16 + l15][ko]);
      #pragma unroll
      for (int ni = 0; ni < 4; ++ni) {
        f16x8 b = *reinterpret_cast<const f16x8*>(&Bs[wc*64 + ni*16 + l15][ko]);
        acc[ni] = __builtin_amdgcn_mfma_f32_16x16x32_f16(a, b, acc[ni], 0, 0, 0);
      }
    }
    __syncthreads();
  }
  #pragma unroll
  for (int v = 0; v < 4; ++v) {
    int gr = r0 + wr*16 + lg*4 + v;
    if (gr < NQn) {
      #pragma unroll
      for (int ni = 0; ni < 4; ++ni)
        C[(size_t)gr*128 + wc*64 + ni*16 + l15] = acc[ni][v];
    }
  }
}

// ---------------------------------------------------------------------------
// Fallback (ws too small): round-1 fused f32 kernel — known-correct.
// ---------------------------------------------------------------------------
__global__ __launch_bounds__(256) void ekp_stage1_fused(
    const float* __restrict__ q_pts, const float* __restrict__ s_pts,
    const int*   __restrict__ nbi,   const float* __restrict__ x,
    const float* __restrict__ q_lrf, const float* __restrict__ s_lrf,
    const float* __restrict__ weights, const float* __restrict__ kp,
    const float* __restrict__ mlp_w, const float* __restrict__ mlp_b,
    float* __restrict__ out)
{
  const int n = blockIdx.x;
  const int tid = threadIdx.x;

  __shared__ float sQ[36];
  __shared__ float sKP[45];
  __shared__ float sMW[36][32];
  __shared__ float sMB[32];
  __shared__ int   sIdx[32];
  __shared__ int   sShad[32];
  __shared__ float sNbr[32][3];
  __shared__ float sLrf[32][37];
  __shared__ float sW[4][15][32];
  __shared__ float sNbx[32][4][65];

  if (tid < 36) sQ[tid]  = q_lrf[(size_t)n*36 + tid];
  if (tid < 45) sKP[tid] = kp[tid];
  if (tid < 32) sMB[tid] = mlp_b[tid];
  for (int i = tid; i < 36*32; i += 256) sMW[i >> 5][i & 31] = mlp_w[i];
  if (tid < 32) {
    int idx = nbi[(size_t)n*Hh + tid];
    int sh = (idx >= NSn) ? 1 : 0;
    sShad[tid] = sh;
    sIdx[tid]  = sh ? 0 : idx;
  }
  __syncthreads();

  if (tid < 96) {
    int h = tid / 3, d = tid - h*3;
    float v = sShad[h] ? 0.f : s_pts[(size_t)sIdx[h]*3 + d];
    sNbr[h][d] = v - q_pts[(size_t)n*3 + d];
  }
  {
    int h = tid >> 3, j0 = tid & 7;
    const float* src = s_lrf + (size_t)sIdx[h]*36;
    float z = sShad[h] ? 0.f : 1.f;
    for (int j = j0; j < 36; j += 8) sLrf[h][j] = z * src[j];
  }
  for (int i = tid; i < Hh*128; i += 256) {
    int h = i >> 7, c = i & 127;
    float v = sShad[h] ? 0.f : x[(size_t)sIdx[h]*128 + c];
    sNbx[h][c >> 5][c & 31] = v;
  }
  __syncthreads();

  {
    int q = tid >> 6, l = tid & 63;
    int h = l & 31, kh = l >> 5;
    float a0 = 0.f, a1 = 0.f, a2 = 0.f;
    #pragma unroll
    for (int d = 0; d < 3; ++d) {
      float nd = sNbr[h][d];
      a0 += nd * sQ[q*9 + d*3 + 0];
      a1 += nd * sQ[q*9 + d*3 + 1];
      a2 += nd * sQ[q*9 + d*3 + 2];
    }
    float z = sShad[h] ? 0.f : 1.f;
    int k0 = kh * 8;
    int kend = k0 + (kh ? 7 : 8);
    for (int k = k0; k < kend; ++k) {
      float d0 = a0 - sKP[k*3+0];
      float d1 = a1 - sKP[k*3+1];
      float d2 = a2 - sKP[k*3+2];
      float wv2 = 1.f - sqrtf(d0*d0 + d1*d1 + d2*d2) * (1.0f/1.2f);
      sW[q][k][h] = z * fmaxf(wv2, 0.f);
    }
  }
  {
    int q = tid >> 6, l = tid & 63;
    int h = l & 31, mh = l >> 5;
    float fi[36];
    #pragma unroll
    for (int s = 0; s < 4; ++s)
      #pragma unroll
      for (int a = 0; a < 3; ++a)
        #pragma unroll
        for (int c = 0; c < 3; ++c) {
          float accv = 0.f;
          #pragma unroll
          for (int b = 0; b < 3; ++b)
            accv += sQ[q*9 + b*3 + a] * sLrf[h][s*9 + b*3 + c];
          fi[s*9 + a*3 + c] = accv;
        }
    float z = sShad[h] ? 0.f : 1.f;
    int m0 = mh * 16;
    for (int mm = 0; mm < 16; ++mm) {
      int m = m0 + mm;
      float accv = sMB[m];
      #pragma unroll
      for (int j = 0; j < 36; ++j) accv += fi[j] * sMW[j][m];
      sNbx[h][q][32 + m] = z * accv;
    }
  }
  __syncthreads();

  float acc[15];
  const int q = tid >> 6, cch = tid & 63;
  #pragma unroll
  for (int k = 0; k < 15; ++k) acc[k] = 0.f;
  for (int h = 0; h < Hh; ++h) {
    float v = sNbx[h][q][cch];
    #pragma unroll
    for (int k = 0; k < 15; ++k) acc[k] += sW[q][k][h] * v;
  }

  __shared__ float sWF[FDIM];
  __shared__ float sRed[2][128];
  #pragma unroll
  for (int k = 0; k < 15; ++k) sWF[k*256 + q*64 + cch] = acc[k];
  __syncthreads();
  int o = tid & 127, part = tid >> 7;
  const float* wp = weights + (size_t)part*1920*128 + o;
  const float* wfp = sWF + part*1920;
  float oa = 0.f;
  #pragma unroll 8
  for (int f = 0; f < 1920; ++f)
    oa += wfp[f] * wp[(size_t)f*128];
  sRed[part][o] = oa;
  __syncthreads();
  if (tid < 128) out[(size_t)n*128 + tid] = sRed[0][tid] + sRed[1][tid];
}

extern "C" void kernel_launch(void* const* d_in, const int* in_sizes, int n_in,
                              void* d_out, int out_size, void* d_ws, size_t ws_size,
                              hipStream_t stream) {
  const float* q_pts   = (const float*)d_in[0];
  const float* s_pts   = (const float*)d_in[1];
  const int*   nbi     = (const int*)  d_in[2];
  const float* x       = (const float*)d_in[3];
  const float* q_lrf   = (const float*)d_in[4];
  const float* s_lrf   = (const float*)d_in[5];
  const float* weights = (const float*)d_in[6];
  const float* kp      = (const float*)d_in[7];
  const float* mlp_w   = (const float*)d_in[8];
  const float* mlp_b   = (const float*)d_in[9];
  float* out = (float*)d_out;

  const size_t nWf = (size_t)NQn * FDIM;
  const size_t nWt = (size_t)128 * FDIM;
  const size_t nXh = (size_t)(NSn + 1) * 128;   // +1 zero row for shadows
  const size_t needBytes = (nWf + nWt + nXh) * sizeof(_Float16);
  if (ws_size >= needBytes) {
    _Float16* wf = (_Float16*)d_ws;
    _Float16* wt = wf + nWf;
    _Float16* xh = wt + nWt;
    ekp_prep5<<<1106, 256, 0, stream>>>(weights, x, wt, xh);
    ekp_stage1h<<<NQn, 256, 0, stream>>>(q_pts, s_pts, nbi,
                                         (const unsigned short*)xh,
                                         q_lrf, s_lrf, kp, mlp_w, mlp_b, wf);
    ekp_gemm3<<<(NQn + 31)/32, 256, 0, stream>>>(wf, wt, out);
  } else {
    ekp_stage1_fused<<<NQn, 256, 0, stream>>>(q_pts, s_pts, nbi, x, q_lrf, s_lrf,
                                              weights, kp, mlp_w, mlp_b, out);
  }
}